// Round 4
// baseline (1483.968 us; speedup 1.0000x reference)
//
#include <hip/hip_runtime.h>
#include <math.h>

// Problem constants
#define Bsz  4096
#define Tlen 512
#define NE   30
#define NIN  5
#define HD10 10
#define B10  (Bsz*HD10)   // per-head plane: 40960 floats

typedef _Float16 h2v __attribute__((ext_vector_type(2)));

__device__ __forceinline__ float fexp2(float x){ return __builtin_amdgcn_exp2f(x); }
__device__ __forceinline__ float frcp (float x){ return __builtin_amdgcn_rcpf(x); }
#define L2E 1.4426950408889634f
__device__ __forceinline__ float sigmoid_fast(float x){ return frcp(1.f + fexp2(-L2E*x)); }
__device__ __forceinline__ float tanh_fast(float x){ return 1.f - 2.f*frcp(1.f + fexp2((2.f*L2E)*x)); }

#if __has_builtin(__builtin_amdgcn_fdot2)
__device__ __forceinline__ float fdot2(h2v a, h2v b, float c){
  return __builtin_amdgcn_fdot2(a, b, c, false);
}
#else
__device__ __forceinline__ float fdot2(h2v a, h2v b, float c){
  return fmaf((float)a.x, (float)b.x, fmaf((float)a.y, (float)b.y, c));
}
#endif

__device__ __forceinline__ h2v bch2(float x){ return __builtin_bit_cast(h2v, x); }

__device__ __forceinline__ void loadarr32(float arr[32], const float* bufrow){
  const float4* p4 = (const float4*)bufrow;
  #pragma unroll
  for (int q4=0;q4<8;q4++){ float4 vv=p4[q4]; arr[4*q4]=vv.x; arr[4*q4+1]=vv.y; arr[4*q4+2]=vv.z; arr[4*q4+3]=vv.w; }
}

// Empty asm that forces each value to live in an arch VGPR at this point.
// Emits ZERO instructions; executed every step it makes an AGPR home cost
// 512 copies, flipping the RA away from AGPR demotion (R3: VGPR_Count=52
// with a 128-reg budget proved weights sat in AGPRs, ~60 accvgpr_read/step).
#define PIN16(A) asm volatile("" \
  : "+v"(A[0]),"+v"(A[1]),"+v"(A[2]),"+v"(A[3]), \
    "+v"(A[4]),"+v"(A[5]),"+v"(A[6]),"+v"(A[7]), \
    "+v"(A[8]),"+v"(A[9]),"+v"(A[10]),"+v"(A[11]), \
    "+v"(A[12]),"+v"(A[13]),"+v"(A[14]),"+v"(A[15]))

// ---------------------------------------------------------------------------
// Kernel 1: fused x-proj + LSTM recurrence + qkv projection.
// One wave per batch element. Lanes: half=lane>>5, j=lane&31.
//   half0,j<30: gates i[j] (acc0) and g[j] (acc1)
//   half1,j<30: gates f[j] (acc0) and o[j] (acc1)
// h state packed fp16 (half2 pairs) in LDS; recurrence matvec via v_dot2_f32_f16
// (fp32 accumulate). Input projection stays fp32. Wave-synchronous.
// ---------------------------------------------------------------------------
extern "C" __global__ void __launch_bounds__(256)
__attribute__((amdgpu_waves_per_eu(4,4)))
lstm_k(const float* __restrict__ input, const float* __restrict__ w_ih,
       const float* __restrict__ w_hh, const float* __restrict__ b_ih,
       const float* __restrict__ b_hh, const float* __restrict__ in_proj_w,
       const float* __restrict__ in_proj_b,
       float* __restrict__ qo, float* __restrict__ ko, float* __restrict__ vo,
       float* __restrict__ ho)
{
  __shared__ __align__(16) float xbuf[4][320];  // 64-step input chunk per wave
  __shared__ __align__(16) float hp[4][16];     // h as 16 packed half2 (pair 15 = 0)
  const int wave = threadIdx.x >> 6;
  const int lane = threadIdx.x & 63;
  const int half = lane >> 5;
  const int j    = lane & 31;
  const int b    = blockIdx.x * 4 + wave;
  const bool act = (j < NE);
  const int g0 = half*NE + j;        // i- or f-row
  const int g1 = 60 + half*NE + j;   // g- or o-row

  // packed fp16 weight pairs (index 15 = zero pad)
  h2v wr0p[16], wr1p[16];
  float wi0[NIN], wi1[NIN];
  float bb0 = 0.f, bb1 = 0.f;
  #pragma unroll
  for (int k2=0;k2<16;k2++){ wr0p[k2]=(h2v)0; wr1p[k2]=(h2v)0; }
  #pragma unroll
  for (int m=0;m<NIN;m++){ wi0[m]=0.f; wi1[m]=0.f; }
  if (act) {
    #pragma unroll
    for (int k2=0;k2<15;k2++){
      h2v w0, w1;
      w0.x = (_Float16)w_hh[g0*NE+2*k2];   w0.y = (_Float16)w_hh[g0*NE+2*k2+1];
      w1.x = (_Float16)w_hh[g1*NE+2*k2];   w1.y = (_Float16)w_hh[g1*NE+2*k2+1];
      wr0p[k2]=w0; wr1p[k2]=w1;
    }
    #pragma unroll
    for (int m=0;m<NIN;m++){ wi0[m]=w_ih[g0*NIN+m]; wi1[m]=w_ih[g1*NIN+m]; }
    bb0 = b_ih[g0]+b_hh[g0];
    bb1 = b_ih[g1]+b_hh[g1];
  }
  if (lane < 16) hp[wave][lane] = 0.f;   // zero-packed h (incl pad pair 15)
  float c = 0.f, hlast = 0.f;
  // half0 -> tanh via 2*sigmoid(2x)-1 ; half1 -> sigmoid(x)
  const float sIn  = half ? 1.f : 2.f;
  const float aMul = half ? 1.f : 2.f;
  const float aAdd = half ? 0.f : -1.f;
  const float* xrow = input + (size_t)b * (Tlen*NIN);
  __builtin_amdgcn_wave_barrier();

  for (int tc = 0; tc < Tlen; tc += 64) {
    // stage 64 steps of input (320 floats) into LDS, coalesced
    #pragma unroll
    for (int r=0;r<5;r++) xbuf[wave][lane + 64*r] = xrow[tc*5 + lane + 64*r];
    __builtin_amdgcn_wave_barrier();
    for (int tl=0; tl<64; ++tl) {
      PIN16(wr0p);
      PIN16(wr1p);
      const float x0 = xbuf[wave][tl*5+0], x1v = xbuf[wave][tl*5+1],
                  x2v = xbuf[wave][tl*5+2], x3v = xbuf[wave][tl*5+3],
                  x4v = xbuf[wave][tl*5+4];
      float a0a = bb0, a0b = 0.f, a1a = bb1, a1b = 0.f;
      a0a = fmaf(wi0[0],x0,a0a);  a1a = fmaf(wi1[0],x0,a1a);
      a0b = fmaf(wi0[1],x1v,a0b); a1b = fmaf(wi1[1],x1v,a1b);
      a0a = fmaf(wi0[2],x2v,a0a); a1a = fmaf(wi1[2],x2v,a1a);
      a0b = fmaf(wi0[3],x3v,a0b); a1b = fmaf(wi1[3],x3v,a1b);
      a0a = fmaf(wi0[4],x4v,a0a); a1a = fmaf(wi1[4],x4v,a1a);
      // h matvec: 16 packed pairs via 4x ds_read_b128, v_dot2_f32_f16
      const float4* hp4 = (const float4*)&hp[wave][0];
      #pragma unroll
      for (int q=0;q<4;q++){
        float4 hv = hp4[q];
        h2v h0=bch2(hv.x), h1=bch2(hv.y), hq2=bch2(hv.z), h3=bch2(hv.w);
        a0a = fdot2(wr0p[4*q+0], h0,  a0a);
        a0b = fdot2(wr0p[4*q+1], h1,  a0b);
        a1a = fdot2(wr1p[4*q+0], h0,  a1a);
        a1b = fdot2(wr1p[4*q+1], h1,  a1b);
        a0a = fdot2(wr0p[4*q+2], hq2, a0a);
        a0b = fdot2(wr0p[4*q+3], h3,  a0b);
        a1a = fdot2(wr1p[4*q+2], hq2, a1a);
        a1b = fdot2(wr1p[4*q+3], h3,  a1b);
      }
      const float ac0 = a0a + a0b;
      const float ac1 = a1a + a1b;
      const float s0 = sigmoid_fast(ac0);               // i (half0) or f (half1)
      const float ss = sigmoid_fast(sIn*ac1);
      const float go = fmaf(aMul, ss, aAdd);            // g (half0) or o (half1)
      const float o0 = __shfl_xor(s0, 32);
      const float o1 = __shfl_xor(go, 32);
      const float iv = half ? o0 : s0;
      const float fv = half ? s0 : o0;
      const float gv = half ? o1 : go;
      const float ov = half ? go : o1;
      c = fmaf(fv, c, iv*gv);
      const float hnew = ov * tanh_fast(c);
      hlast = hnew;
      const float hup = __shfl_xor(hnew, 1);            // partner for packing
      if (half==0 && act && !(j&1)) {
        h2v pk; pk.x = (_Float16)hnew; pk.y = (_Float16)hup;
        hp[wave][j>>1] = __builtin_bit_cast(float, pk);
      }
      __builtin_amdgcn_wave_barrier();
    }
  }

  // ---- tail: q = h@Wq^T+bq (pre-scaled by 1/sqrt(HD)); k,v from c ----
  float* cbuf = &xbuf[wave][0];     // c fp32, 32 slots zero-padded
  float* hb32 = &xbuf[wave][32];    // h fp32, 32 slots zero-padded
  if (half==0) { cbuf[lane] = act ? c : 0.f; hb32[lane] = act ? hlast : 0.f; }
  __builtin_amdgcn_wave_barrier();
  if (half==0 && act) ho[b*NE + j] = hlast;
  const float QS = 0.31622776601683794f;     // 1/sqrt(10)
  #pragma unroll
  for (int rep=0; rep<2; ++rep) {
    const int o = lane + rep*64;
    if (o < 90) {
      const float* wrow = in_proj_w + o*NE;
      const float* src  = (o < NE) ? hb32 : cbuf;
      float acc = in_proj_b[o];
      #pragma unroll
      for (int k2=0;k2<NE;k2++) acc = fmaf(wrow[k2], src[k2], acc);
      if (o < 30)      { qo[(o/10)*B10 + b*10 + (o%10)] = acc * QS; }
      else if (o < 60) { const int u=o-30; ko[(u/10)*B10 + b*10 + (u%10)] = acc; }
      else             { const int u=o-60; vo[(u/10)*B10 + b*10 + (u%10)] = acc; }
    }
  }
}

// ---------------------------------------------------------------------------
// Kernel 2: flash-style attention over the batch axis. grid=(64 qtiles, 3 heads),
// block=1024 (16 waves, 4/SIMD for latency hiding). 128-key tiles double-
// buffered in FOUR DISTINCT __shared__ arrays (R3's single array indexed by
// runtime cur/nxt defeated alias analysis -> staging ds_write+vmcnt could not
// sink below compute -> every tile paid full memory latency serially).
// Source order per tile: global loads -> compute(cur) -> LDS store(nxt) -> barrier.
// Each wave handles 8 keys/tile for 64 query rows (lane = q row, LDS reads are
// wave-uniform broadcasts). Online softmax per thread; two-stage LDS merge
// (16 -> 8 -> 1 partials per query) keeps static LDS at 44 KB (< 64 KB limit).
// ---------------------------------------------------------------------------
extern "C" __global__ void __launch_bounds__(1024)
__attribute__((amdgpu_waves_per_eu(4,4)))
attn_k(const float* __restrict__ q, const float* __restrict__ k,
       const float* __restrict__ v, float* __restrict__ ctx)
{
  __shared__ __align__(16) float ktb0[1280];
  __shared__ __align__(16) float ktb1[1280];
  __shared__ __align__(16) float vtb0[1280];
  __shared__ __align__(16) float vtb1[1280];
  __shared__ float red[8][64][12];
  const int t    = threadIdx.x;
  const int ql   = t & 63;
  const int w    = t >> 6;          // 0..15
  const int head = blockIdx.y;
  const int qr   = blockIdx.x*64 + ql;
  const float* kh = k + (size_t)head*B10;
  const float* vh = v + (size_t)head*B10;
  float qreg[10];
  {
    const float2* qp = (const float2*)(q + (size_t)head*B10 + qr*10);
    #pragma unroll
    for (int i=0;i<5;i++){ float2 t2=qp[i]; qreg[2*i]=t2.x; qreg[2*i+1]=t2.y; }
  }
  float m = -INFINITY, l = 0.f, acc[10];
  #pragma unroll
  for (int d=0;d<10;d++) acc[d]=0.f;

  auto sload = [&](int ti, float4& ra){
    if (ti < 32) {
      if (t < 320)      ra = ((const float4*)(kh + (size_t)ti*1280))[t];
      else if (t < 640) ra = ((const float4*)(vh + (size_t)ti*1280))[t-320];
    }
  };
  auto sstore = [&](int ti, float4 ra, float* __restrict__ nk, float* __restrict__ nv){
    if (ti < 32) {
      if (t < 320)      ((float4*)nk)[t]     = ra;
      else if (t < 640) ((float4*)nv)[t-320] = ra;
    }
  };
  auto tcomp = [&](const float* __restrict__ ck, const float* __restrict__ cv){
    const float* kb = ck + w*80;   // this wave's 8 keys (8 x 10 floats)
    const float* vb = cv + w*80;
    float s[8];
    #pragma unroll
    for (int u=0;u<8;u++){
      const float2* kp = (const float2*)(kb + u*10);
      float sv = 0.f;
      #pragma unroll
      for (int i=0;i<5;i++){ float2 kk=kp[i]; sv=fmaf(qreg[2*i],kk.x,sv); sv=fmaf(qreg[2*i+1],kk.y,sv); }
      s[u]=sv;
    }
    float mc = s[0];
    #pragma unroll
    for (int u=1;u<8;u++) mc = fmaxf(mc, s[u]);
    const float mnew = fmaxf(m, mc);
    const float corr = fexp2(L2E*(m - mnew));   // m=-inf first tile -> 0
    l *= corr;
    #pragma unroll
    for (int d=0;d<10;d++) acc[d]*=corr;
    #pragma unroll
    for (int u=0;u<8;u++){
      const float p = fexp2(L2E*(s[u]-mnew));
      l += p;
      const float2* vp = (const float2*)(vb + u*10);
      #pragma unroll
      for (int i=0;i<5;i++){ float2 vv=vp[i]; acc[2*i]=fmaf(p,vv.x,acc[2*i]); acc[2*i+1]=fmaf(p,vv.y,acc[2*i+1]); }
    }
    m = mnew;
  };

  {
    float4 r0 = make_float4(0.f,0.f,0.f,0.f);
    sload(0, r0);
    sstore(0, r0, ktb0, vtb0);
  }
  __syncthreads();
  for (int ti=0; ti<32; ti+=2){
    {
      float4 ra = make_float4(0.f,0.f,0.f,0.f);
      sload(ti+1, ra);          // issue global loads early
      tcomp(ktb0, vtb0);        // compute overlaps load latency
      sstore(ti+1, ra, ktb1, vtb1);
      __syncthreads();
    }
    {
      float4 rb = make_float4(0.f,0.f,0.f,0.f);
      sload(ti+2, rb);
      tcomp(ktb1, vtb1);
      sstore(ti+2, rb, ktb0, vtb0);
      __syncthreads();
    }
  }
  // merge stage 1: fold waves 8..15 into 0..7
  if (w >= 8) {
    red[w-8][ql][0]=m; red[w-8][ql][1]=l;
    #pragma unroll
    for (int d=0;d<10;d++) red[w-8][ql][2+d]=acc[d];
  }
  __syncthreads();
  if (w < 8) {
    const float m2 = red[w][ql][0], l2 = red[w][ql][1];
    const float M  = fmaxf(m, m2);
    const float wa = fexp2(L2E*(m - M));
    const float wb = fexp2(L2E*(m2 - M));
    l = l*wa + l2*wb;
    #pragma unroll
    for (int d=0;d<10;d++) acc[d] = acc[d]*wa + red[w][ql][2+d]*wb;
    red[w][ql][0]=M; red[w][ql][1]=l;
    #pragma unroll
    for (int d=0;d<10;d++) red[w][ql][2+d]=acc[d];
  }
  __syncthreads();
  // merge stage 2: fold the 8 partials per query
  if (t < 64) {
    float M = red[0][t][0];
    #pragma unroll
    for (int i=1;i<8;i++) M = fmaxf(M, red[i][t][0]);
    float L=0.f, o[10];
    #pragma unroll
    for (int d=0;d<10;d++) o[d]=0.f;
    #pragma unroll
    for (int i=0;i<8;i++){
      const float wgt = fexp2(L2E*(red[i][t][0]-M));
      L = fmaf(red[i][t][1], wgt, L);
      #pragma unroll
      for (int d=0;d<10;d++) o[d]=fmaf(red[i][t][2+d],wgt,o[d]);
    }
    const float invL = 1.f/L;
    float* cp = ctx + (size_t)head*B10 + (size_t)(blockIdx.x*64 + t)*10;
    #pragma unroll
    for (int d=0;d<10;d++) cp[d]=o[d]*invL;
  }
}

// ---------------------------------------------------------------------------
// Kernel 3: out_proj + residual + LN + MLP(exact GELU) + LN + head.
// One wave per row; row vector staged in a per-wave 32-float LDS buffer.
// ---------------------------------------------------------------------------
extern "C" __global__ void __launch_bounds__(256)
tail_k(const float* __restrict__ ctx, const float* __restrict__ hn,
       const float* __restrict__ out_proj_w, const float* __restrict__ out_proj_b,
       const float* __restrict__ fc1_w, const float* __restrict__ fc1_b,
       const float* __restrict__ fc2_w, const float* __restrict__ fc2_b,
       const float* __restrict__ ln_g, const float* __restrict__ ln_b,
       const float* __restrict__ out_w, const float* __restrict__ out_b,
       float* __restrict__ out)
{
  __shared__ __align__(16) float buf[4][32];
  const int wave = threadIdx.x >> 6;
  const int lane = threadIdx.x & 63;
  const int b = blockIdx.x*4 + wave;
  const bool act = (lane < NE);
  if (lane < 32) buf[wave][lane] = 0.f;
  __builtin_amdgcn_wave_barrier();
  if (act) buf[wave][lane] = ctx[(lane/10)*B10 + b*10 + (lane%10)];
  __builtin_amdgcn_wave_barrier();
  float arr[32];
  loadarr32(arr, &buf[wave][0]);
  const float hv = act ? hn[b*NE+lane] : 0.f;
  float x = 0.f;
  if (act) {
    float a = out_proj_b[lane];
    #pragma unroll
    for (int k2=0;k2<NE;k2++) a = fmaf(out_proj_w[lane*NE+k2], arr[k2], a);
    x = a + hv;                       // attn_out + h_n
  }
  // LN1
  __builtin_amdgcn_wave_barrier();
  if (act) buf[wave][lane] = x;
  __builtin_amdgcn_wave_barrier();
  loadarr32(arr, &buf[wave][0]);
  float s1=0.f, s2=0.f;
  #pragma unroll
  for (int k2=0;k2<32;k2++){ s1+=arr[k2]; s2=fmaf(arr[k2],arr[k2],s2); }
  float mu = s1*(1.f/30.f);
  float var = s2*(1.f/30.f) - mu*mu;
  float rs = rsqrtf(var + 1e-5f);
  float x1 = 0.f;
  if (act) x1 = fmaf((x-mu)*rs, ln_g[lane], ln_b[lane]);
  // fc1 + exact GELU
  __builtin_amdgcn_wave_barrier();
  if (act) buf[wave][lane] = x1;
  __builtin_amdgcn_wave_barrier();
  loadarr32(arr, &buf[wave][0]);
  float gv = 0.f;
  if (act) {
    float a = fc1_b[lane];
    #pragma unroll
    for (int k2=0;k2<NE;k2++) a = fmaf(fc1_w[lane*NE+k2], arr[k2], a);
    gv = 0.5f*a*(1.f + erff(a*0.70710678118654752f));
  }
  // fc2
  __builtin_amdgcn_wave_barrier();
  if (act) buf[wave][lane] = gv;
  __builtin_amdgcn_wave_barrier();
  loadarr32(arr, &buf[wave][0]);
  float y = 0.f;
  if (act) {
    float a = fc2_b[lane];
    #pragma unroll
    for (int k2=0;k2<NE;k2++) a = fmaf(fc2_w[lane*NE+k2], arr[k2], a);
    y = x1 + a;                        // residual x1 + fc
  }
  // LN2
  __builtin_amdgcn_wave_barrier();
  if (act) buf[wave][lane] = y;
  __builtin_amdgcn_wave_barrier();
  loadarr32(arr, &buf[wave][0]);
  s1=0.f; s2=0.f;
  #pragma unroll
  for (int k2=0;k2<32;k2++){ s1+=arr[k2]; s2=fmaf(arr[k2],arr[k2],s2); }
  mu = s1*(1.f/30.f);
  var = s2*(1.f/30.f) - mu*mu;
  rs = rsqrtf(var + 1e-5f);
  float x2 = 0.f;
  if (act) x2 = fmaf((y-mu)*rs, ln_g[lane], ln_b[lane]);
  // head: [3,30]
  __builtin_amdgcn_wave_barrier();
  if (act) buf[wave][lane] = x2;
  __builtin_amdgcn_wave_barrier();
  loadarr32(arr, &buf[wave][0]);
  if (lane < 3) {
    float a = out_b[lane];
    #pragma unroll
    for (int k2=0;k2<NE;k2++) a = fmaf(out_w[lane*NE+k2], arr[k2], a);
    out[b*3 + lane] = a;
  }
}

extern "C" void kernel_launch(void* const* d_in, const int* in_sizes, int n_in,
                              void* d_out, int out_size, void* d_ws, size_t ws_size,
                              hipStream_t stream)
{
  const float* input      = (const float*)d_in[0];
  const float* w_ih       = (const float*)d_in[1];
  const float* w_hh       = (const float*)d_in[2];
  const float* b_ih       = (const float*)d_in[3];
  const float* b_hh       = (const float*)d_in[4];
  const float* in_proj_w  = (const float*)d_in[5];
  const float* in_proj_b  = (const float*)d_in[6];
  const float* out_proj_w = (const float*)d_in[7];
  const float* out_proj_b = (const float*)d_in[8];
  const float* fc1_w      = (const float*)d_in[9];
  const float* fc1_b      = (const float*)d_in[10];
  const float* fc2_w      = (const float*)d_in[11];
  const float* fc2_b      = (const float*)d_in[12];
  const float* ln_g       = (const float*)d_in[13];
  const float* ln_b       = (const float*)d_in[14];
  const float* out_w      = (const float*)d_in[15];
  const float* out_b      = (const float*)d_in[16];

  float* ws = (float*)d_ws;
  float* qo = ws;                 // [3][4096][10]
  float* ko = ws + 122880;        // [3][4096][10]
  float* vo = ws + 245760;        // [3][4096][10]
  float* hn = ws + 368640;        // [4096][30]
  float* cx = ws + 491520;        // [3][4096][10]

  lstm_k<<<Bsz/4, 256, 0, stream>>>(input, w_ih, w_hh, b_ih, b_hh,
                                    in_proj_w, in_proj_b, qo, ko, vo, hn);
  attn_k<<<dim3(Bsz/64, 3), 1024, 0, stream>>>(qo, ko, vo, cx);
  tail_k<<<Bsz/4, 256, 0, stream>>>(cx, hn, out_proj_w, out_proj_b,
                                    fc1_w, fc1_b, fc2_w, fc2_b,
                                    ln_g, ln_b, out_w, out_b, (float*)d_out);
}

// Round 5
// 522.991 us; speedup vs baseline: 2.8375x; 2.8375x over previous
//
#include <hip/hip_runtime.h>
#include <math.h>

// Problem constants
#define Bsz  4096
#define Tlen 512
#define NE   30
#define NIN  5
#define HD10 10
#define B10  (Bsz*HD10)   // per-head plane: 40960 floats
#define KSPLIT 8

typedef _Float16 h2v __attribute__((ext_vector_type(2)));

__device__ __forceinline__ float fexp2(float x){ return __builtin_amdgcn_exp2f(x); }
__device__ __forceinline__ float frcp (float x){ return __builtin_amdgcn_rcpf(x); }
#define L2E 1.4426950408889634f
__device__ __forceinline__ float sigmoid_fast(float x){ return frcp(1.f + fexp2(-L2E*x)); }
__device__ __forceinline__ float tanh_fast(float x){ return 1.f - 2.f*frcp(1.f + fexp2((2.f*L2E)*x)); }

#if __has_builtin(__builtin_amdgcn_fdot2)
__device__ __forceinline__ float fdot2(h2v a, h2v b, float c){
  return __builtin_amdgcn_fdot2(a, b, c, false);
}
#else
__device__ __forceinline__ float fdot2(h2v a, h2v b, float c){
  return fmaf((float)a.x, (float)b.x, fmaf((float)a.y, (float)b.y, c));
}
#endif

__device__ __forceinline__ h2v bch2(float x){ return __builtin_bit_cast(h2v, x); }

__device__ __forceinline__ void loadarr32(float arr[32], const float* bufrow){
  const float4* p4 = (const float4*)bufrow;
  #pragma unroll
  for (int q4=0;q4<8;q4++){ float4 vv=p4[q4]; arr[4*q4]=vv.x; arr[4*q4+1]=vv.y; arr[4*q4+2]=vv.z; arr[4*q4+3]=vv.w; }
}

// ---------------------------------------------------------------------------
// Kernel 1: fused x-proj + LSTM recurrence + qkv projection.
// One wave per batch element. Lanes: half=lane>>5, j=lane&31.
//   half0,j<30: gates i[j] (acc0) and g[j] (acc1)
//   half1,j<30: gates f[j] (acc0) and o[j] (acc1)
// h state packed fp16 (half2 pairs) in LDS; recurrence matvec via v_dot2_f32_f16
// (fp32 accumulate). Input projection stays fp32. Wave-synchronous.
// R4 lesson: PIN16 asm pinning regressed (~440us) - removed. #pragma unroll 1
// keeps per-iteration register pressure minimal to discourage the RA from
// demoting the 32 weight regs to AGPRs (R2/R3: VGPR_Count=52 -> accvgpr_read tax).
// ---------------------------------------------------------------------------
extern "C" __global__ void __launch_bounds__(256)
__attribute__((amdgpu_waves_per_eu(4,4)))
lstm_k(const float* __restrict__ input, const float* __restrict__ w_ih,
       const float* __restrict__ w_hh, const float* __restrict__ b_ih,
       const float* __restrict__ b_hh, const float* __restrict__ in_proj_w,
       const float* __restrict__ in_proj_b,
       float* __restrict__ qo, float* __restrict__ ko, float* __restrict__ vo,
       float* __restrict__ ho)
{
  __shared__ __align__(16) float xbuf[4][320];  // 64-step input chunk per wave
  __shared__ __align__(16) float hp[4][16];     // h as 16 packed half2 (pair 15 = 0)
  const int wave = threadIdx.x >> 6;
  const int lane = threadIdx.x & 63;
  const int half = lane >> 5;
  const int j    = lane & 31;
  const int b    = blockIdx.x * 4 + wave;
  const bool act = (j < NE);
  const int g0 = half*NE + j;        // i- or f-row
  const int g1 = 60 + half*NE + j;   // g- or o-row

  // packed fp16 weight pairs (index 15 = zero pad)
  h2v wr0p[16], wr1p[16];
  float wi0[NIN], wi1[NIN];
  float bb0 = 0.f, bb1 = 0.f;
  #pragma unroll
  for (int k2=0;k2<16;k2++){ wr0p[k2]=(h2v)0; wr1p[k2]=(h2v)0; }
  #pragma unroll
  for (int m=0;m<NIN;m++){ wi0[m]=0.f; wi1[m]=0.f; }
  if (act) {
    #pragma unroll
    for (int k2=0;k2<15;k2++){
      h2v w0, w1;
      w0.x = (_Float16)w_hh[g0*NE+2*k2];   w0.y = (_Float16)w_hh[g0*NE+2*k2+1];
      w1.x = (_Float16)w_hh[g1*NE+2*k2];   w1.y = (_Float16)w_hh[g1*NE+2*k2+1];
      wr0p[k2]=w0; wr1p[k2]=w1;
    }
    #pragma unroll
    for (int m=0;m<NIN;m++){ wi0[m]=w_ih[g0*NIN+m]; wi1[m]=w_ih[g1*NIN+m]; }
    bb0 = b_ih[g0]+b_hh[g0];
    bb1 = b_ih[g1]+b_hh[g1];
  }
  if (lane < 16) hp[wave][lane] = 0.f;   // zero-packed h (incl pad pair 15)
  float c = 0.f, hlast = 0.f;
  // half0 -> tanh via 2*sigmoid(2x)-1 ; half1 -> sigmoid(x)
  const float sIn  = half ? 1.f : 2.f;
  const float aMul = half ? 1.f : 2.f;
  const float aAdd = half ? 0.f : -1.f;
  const float* xrow = input + (size_t)b * (Tlen*NIN);
  __builtin_amdgcn_wave_barrier();

  for (int tc = 0; tc < Tlen; tc += 64) {
    // stage 64 steps of input (320 floats) into LDS, coalesced
    #pragma unroll
    for (int r=0;r<5;r++) xbuf[wave][lane + 64*r] = xrow[tc*5 + lane + 64*r];
    __builtin_amdgcn_wave_barrier();
    #pragma unroll 1
    for (int tl=0; tl<64; ++tl) {
      const float x0 = xbuf[wave][tl*5+0], x1v = xbuf[wave][tl*5+1],
                  x2v = xbuf[wave][tl*5+2], x3v = xbuf[wave][tl*5+3],
                  x4v = xbuf[wave][tl*5+4];
      float a0a = bb0, a0b = 0.f, a1a = bb1, a1b = 0.f;
      a0a = fmaf(wi0[0],x0,a0a);  a1a = fmaf(wi1[0],x0,a1a);
      a0b = fmaf(wi0[1],x1v,a0b); a1b = fmaf(wi1[1],x1v,a1b);
      a0a = fmaf(wi0[2],x2v,a0a); a1a = fmaf(wi1[2],x2v,a1a);
      a0b = fmaf(wi0[3],x3v,a0b); a1b = fmaf(wi1[3],x3v,a1b);
      a0a = fmaf(wi0[4],x4v,a0a); a1a = fmaf(wi1[4],x4v,a1a);
      // h matvec: 16 packed pairs via 4x ds_read_b128, v_dot2_f32_f16
      const float4* hp4 = (const float4*)&hp[wave][0];
      #pragma unroll
      for (int q=0;q<4;q++){
        float4 hv = hp4[q];
        h2v h0=bch2(hv.x), h1=bch2(hv.y), hq2=bch2(hv.z), h3=bch2(hv.w);
        a0a = fdot2(wr0p[4*q+0], h0,  a0a);
        a0b = fdot2(wr0p[4*q+1], h1,  a0b);
        a1a = fdot2(wr1p[4*q+0], h0,  a1a);
        a1b = fdot2(wr1p[4*q+1], h1,  a1b);
        a0a = fdot2(wr0p[4*q+2], hq2, a0a);
        a0b = fdot2(wr0p[4*q+3], h3,  a0b);
        a1a = fdot2(wr1p[4*q+2], hq2, a1a);
        a1b = fdot2(wr1p[4*q+3], h3,  a1b);
      }
      const float ac0 = a0a + a0b;
      const float ac1 = a1a + a1b;
      const float s0 = sigmoid_fast(ac0);               // i (half0) or f (half1)
      const float ss = sigmoid_fast(sIn*ac1);
      const float go = fmaf(aMul, ss, aAdd);            // g (half0) or o (half1)
      const float o0 = __shfl_xor(s0, 32);
      const float o1 = __shfl_xor(go, 32);
      const float iv = half ? o0 : s0;
      const float fv = half ? s0 : o0;
      const float gv = half ? o1 : go;
      const float ov = half ? go : o1;
      c = fmaf(fv, c, iv*gv);
      const float hnew = ov * tanh_fast(c);
      hlast = hnew;
      const float hup = __shfl_xor(hnew, 1);            // partner for packing
      if (half==0 && act && !(j&1)) {
        h2v pk; pk.x = (_Float16)hnew; pk.y = (_Float16)hup;
        hp[wave][j>>1] = __builtin_bit_cast(float, pk);
      }
      __builtin_amdgcn_wave_barrier();
    }
  }

  // ---- tail: q = h@Wq^T+bq (pre-scaled by 1/sqrt(HD)); k,v from c ----
  float* cbuf = &xbuf[wave][0];     // c fp32, 32 slots zero-padded
  float* hb32 = &xbuf[wave][32];    // h fp32, 32 slots zero-padded
  if (half==0) { cbuf[lane] = act ? c : 0.f; hb32[lane] = act ? hlast : 0.f; }
  __builtin_amdgcn_wave_barrier();
  if (half==0 && act) ho[b*NE + j] = hlast;
  const float QS = 0.31622776601683794f;     // 1/sqrt(10)
  #pragma unroll
  for (int rep=0; rep<2; ++rep) {
    const int o = lane + rep*64;
    if (o < 90) {
      const float* wrow = in_proj_w + o*NE;
      const float* src  = (o < NE) ? hb32 : cbuf;
      float acc = in_proj_b[o];
      #pragma unroll
      for (int k2=0;k2<NE;k2++) acc = fmaf(wrow[k2], src[k2], acc);
      if (o < 30)      { qo[(o/10)*B10 + b*10 + (o%10)] = acc * QS; }
      else if (o < 60) { const int u=o-30; ko[(u/10)*B10 + b*10 + (u%10)] = acc; }
      else             { const int u=o-60; vo[(u/10)*B10 + b*10 + (u%10)] = acc; }
    }
  }
}

// ---------------------------------------------------------------------------
// Kernel 2a: flash attention partials. 1 thread = 1 query row.
// grid = (16 qblocks, 3 heads, KSPLIT ksplits), block = 256 (4 waves).
// Key/value addresses depend only on (blockIdx, loop counter) -> fully
// wave-uniform -> compiler emits scalar s_loads / broadcast loads: zero
// per-lane memory traffic, no LDS staging, no spill-prone state.
// Each thread streams 4096/KSPLIT keys with online softmax, writes a
// 12-float partial (m, l, acc[10]) per (head, query, ksplit).
// R4 lesson: 1024-thr block + waves_per_eu(4,4) caused VGPR=64 + 2.9GB
// scratch thrash -> plain 256-thr block, no occupancy attributes.
// ---------------------------------------------------------------------------
extern "C" __global__ void __launch_bounds__(256)
attn_part(const float* __restrict__ q, const float* __restrict__ k,
          const float* __restrict__ v, float* __restrict__ part)
{
  const int t    = threadIdx.x;
  const int qr   = blockIdx.x*256 + t;
  const int head = blockIdx.y;
  const int ks   = blockIdx.z;
  const float* kh = k + (size_t)head*B10;
  const float* vh = v + (size_t)head*B10;
  float qreg[10];
  {
    const float2* qp = (const float2*)(q + (size_t)head*B10 + (size_t)qr*10);
    #pragma unroll
    for (int i=0;i<5;i++){ float2 t2=qp[i]; qreg[2*i]=t2.x; qreg[2*i+1]=t2.y; }
  }
  float m = -INFINITY, l = 0.f, acc[10];
  #pragma unroll
  for (int d=0;d<10;d++) acc[d]=0.f;

  const int k0 = ks * (Bsz/KSPLIT);
  #pragma unroll 1
  for (int cch=0; cch<Bsz/KSPLIT; cch+=8) {
    const int kb = k0 + cch;           // wave-uniform
    float s[8];
    #pragma unroll
    for (int u=0;u<8;u++){
      const float* kp = kh + (size_t)(kb+u)*10;
      float sv = 0.f;
      #pragma unroll
      for (int i=0;i<10;i++) sv = fmaf(qreg[i], kp[i], sv);
      s[u]=sv;
    }
    float mc = s[0];
    #pragma unroll
    for (int u=1;u<8;u++) mc = fmaxf(mc, s[u]);
    const float mnew = fmaxf(m, mc);
    const float corr = fexp2(L2E*(m - mnew));   // m=-inf first chunk -> 0
    l *= corr;
    #pragma unroll
    for (int d=0;d<10;d++) acc[d]*=corr;
    #pragma unroll
    for (int u=0;u<8;u++){
      const float p = fexp2(L2E*(s[u]-mnew));
      l += p;
      const float* vp = vh + (size_t)(kb+u)*10;
      #pragma unroll
      for (int d=0;d<10;d++) acc[d] = fmaf(p, vp[d], acc[d]);
    }
    m = mnew;
  }
  float* pp = part + ((size_t)(head*Bsz + qr)*KSPLIT + ks)*12;
  pp[0]=m; pp[1]=l;
  #pragma unroll
  for (int d=0;d<10;d++) pp[2+d]=acc[d];
}

// ---------------------------------------------------------------------------
// Kernel 2b: merge KSPLIT partials per (head, query) -> ctx.
// 12288 threads, one per (head, query).
// ---------------------------------------------------------------------------
extern "C" __global__ void __launch_bounds__(256)
attn_merge(const float* __restrict__ part, float* __restrict__ ctx)
{
  const int id = blockIdx.x*256 + threadIdx.x;   // 0..12287
  const int head = id >> 12;
  const int qr   = id & 4095;
  const float* p = part + (size_t)id*KSPLIT*12;
  float M = p[0];
  #pragma unroll
  for (int i=1;i<KSPLIT;i++) M = fmaxf(M, p[i*12]);
  float L=0.f, o[10];
  #pragma unroll
  for (int d=0;d<10;d++) o[d]=0.f;
  #pragma unroll
  for (int i=0;i<KSPLIT;i++){
    const float w = fexp2(L2E*(p[i*12]-M));
    L = fmaf(p[i*12+1], w, L);
    #pragma unroll
    for (int d=0;d<10;d++) o[d]=fmaf(p[i*12+2+d],w,o[d]);
  }
  const float invL = 1.f/L;
  float* cp = ctx + (size_t)head*B10 + (size_t)qr*10;
  #pragma unroll
  for (int d=0;d<10;d++) cp[d]=o[d]*invL;
}

// ---------------------------------------------------------------------------
// Kernel 3: out_proj + residual + LN + MLP(exact GELU) + LN + head.
// One wave per row; row vector staged in a per-wave 32-float LDS buffer.
// ---------------------------------------------------------------------------
extern "C" __global__ void __launch_bounds__(256)
tail_k(const float* __restrict__ ctx, const float* __restrict__ hn,
       const float* __restrict__ out_proj_w, const float* __restrict__ out_proj_b,
       const float* __restrict__ fc1_w, const float* __restrict__ fc1_b,
       const float* __restrict__ fc2_w, const float* __restrict__ fc2_b,
       const float* __restrict__ ln_g, const float* __restrict__ ln_b,
       const float* __restrict__ out_w, const float* __restrict__ out_b,
       float* __restrict__ out)
{
  __shared__ __align__(16) float buf[4][32];
  const int wave = threadIdx.x >> 6;
  const int lane = threadIdx.x & 63;
  const int b = blockIdx.x*4 + wave;
  const bool act = (lane < NE);
  if (lane < 32) buf[wave][lane] = 0.f;
  __builtin_amdgcn_wave_barrier();
  if (act) buf[wave][lane] = ctx[(lane/10)*B10 + b*10 + (lane%10)];
  __builtin_amdgcn_wave_barrier();
  float arr[32];
  loadarr32(arr, &buf[wave][0]);
  const float hv = act ? hn[b*NE+lane] : 0.f;
  float x = 0.f;
  if (act) {
    float a = out_proj_b[lane];
    #pragma unroll
    for (int k2=0;k2<NE;k2++) a = fmaf(out_proj_w[lane*NE+k2], arr[k2], a);
    x = a + hv;                       // attn_out + h_n
  }
  // LN1
  __builtin_amdgcn_wave_barrier();
  if (act) buf[wave][lane] = x;
  __builtin_amdgcn_wave_barrier();
  loadarr32(arr, &buf[wave][0]);
  float s1=0.f, s2=0.f;
  #pragma unroll
  for (int k2=0;k2<32;k2++){ s1+=arr[k2]; s2=fmaf(arr[k2],arr[k2],s2); }
  float mu = s1*(1.f/30.f);
  float var = s2*(1.f/30.f) - mu*mu;
  float rs = rsqrtf(var + 1e-5f);
  float x1 = 0.f;
  if (act) x1 = fmaf((x-mu)*rs, ln_g[lane], ln_b[lane]);
  // fc1 + exact GELU
  __builtin_amdgcn_wave_barrier();
  if (act) buf[wave][lane] = x1;
  __builtin_amdgcn_wave_barrier();
  loadarr32(arr, &buf[wave][0]);
  float gv = 0.f;
  if (act) {
    float a = fc1_b[lane];
    #pragma unroll
    for (int k2=0;k2<NE;k2++) a = fmaf(fc1_w[lane*NE+k2], arr[k2], a);
    gv = 0.5f*a*(1.f + erff(a*0.70710678118654752f));
  }
  // fc2
  __builtin_amdgcn_wave_barrier();
  if (act) buf[wave][lane] = gv;
  __builtin_amdgcn_wave_barrier();
  loadarr32(arr, &buf[wave][0]);
  float y = 0.f;
  if (act) {
    float a = fc2_b[lane];
    #pragma unroll
    for (int k2=0;k2<NE;k2++) a = fmaf(fc2_w[lane*NE+k2], arr[k2], a);
    y = x1 + a;                        // residual x1 + fc
  }
  // LN2
  __builtin_amdgcn_wave_barrier();
  if (act) buf[wave][lane] = y;
  __builtin_amdgcn_wave_barrier();
  loadarr32(arr, &buf[wave][0]);
  s1=0.f; s2=0.f;
  #pragma unroll
  for (int k2=0;k2<32;k2++){ s1+=arr[k2]; s2=fmaf(arr[k2],arr[k2],s2); }
  mu = s1*(1.f/30.f);
  var = s2*(1.f/30.f) - mu*mu;
  rs = rsqrtf(var + 1e-5f);
  float x2 = 0.f;
  if (act) x2 = fmaf((y-mu)*rs, ln_g[lane], ln_b[lane]);
  // head: [3,30]
  __builtin_amdgcn_wave_barrier();
  if (act) buf[wave][lane] = x2;
  __builtin_amdgcn_wave_barrier();
  loadarr32(arr, &buf[wave][0]);
  if (lane < 3) {
    float a = out_b[lane];
    #pragma unroll
    for (int k2=0;k2<NE;k2++) a = fmaf(out_w[lane*NE+k2], arr[k2], a);
    out[b*3 + lane] = a;
  }
}

extern "C" void kernel_launch(void* const* d_in, const int* in_sizes, int n_in,
                              void* d_out, int out_size, void* d_ws, size_t ws_size,
                              hipStream_t stream)
{
  const float* input      = (const float*)d_in[0];
  const float* w_ih       = (const float*)d_in[1];
  const float* w_hh       = (const float*)d_in[2];
  const float* b_ih       = (const float*)d_in[3];
  const float* b_hh       = (const float*)d_in[4];
  const float* in_proj_w  = (const float*)d_in[5];
  const float* in_proj_b  = (const float*)d_in[6];
  const float* out_proj_w = (const float*)d_in[7];
  const float* out_proj_b = (const float*)d_in[8];
  const float* fc1_w      = (const float*)d_in[9];
  const float* fc1_b      = (const float*)d_in[10];
  const float* fc2_w      = (const float*)d_in[11];
  const float* fc2_b      = (const float*)d_in[12];
  const float* ln_g       = (const float*)d_in[13];
  const float* ln_b       = (const float*)d_in[14];
  const float* out_w      = (const float*)d_in[15];
  const float* out_b      = (const float*)d_in[16];

  float* ws = (float*)d_ws;
  float* qo   = ws;                 // [3][4096][10]
  float* ko   = ws + 122880;        // [3][4096][10]
  float* vo   = ws + 245760;        // [3][4096][10]
  float* hn   = ws + 368640;        // [4096][30]
  float* cx   = ws + 491520;        // [3][4096][10]
  float* part = ws + 614400;        // [3][4096][KSPLIT][12] = 1179648 floats

  lstm_k<<<Bsz/4, 256, 0, stream>>>(input, w_ih, w_hh, b_ih, b_hh,
                                    in_proj_w, in_proj_b, qo, ko, vo, hn);
  attn_part<<<dim3(Bsz/256, 3, KSPLIT), 256, 0, stream>>>(qo, ko, vo, part);
  attn_merge<<<(3*Bsz)/256, 256, 0, stream>>>(part, cx);
  tail_k<<<Bsz/4, 256, 0, stream>>>(cx, hn, out_proj_w, out_proj_b,
                                    fc1_w, fc1_b, fc2_w, fc2_b,
                                    ln_g, ln_b, out_w, out_b, (float*)d_out);
}

// Round 6
// 494.651 us; speedup vs baseline: 3.0000x; 1.0573x over previous
//
#include <hip/hip_runtime.h>
#include <math.h>

// Problem constants
#define Bsz  4096
#define Tlen 512
#define NE   30
#define NIN  5
#define HD10 10
#define B10  (Bsz*HD10)   // per-head plane: 40960 floats

typedef _Float16 h2v __attribute__((ext_vector_type(2)));

__device__ __forceinline__ float fexp2(float x){ return __builtin_amdgcn_exp2f(x); }
__device__ __forceinline__ float frcp (float x){ return __builtin_amdgcn_rcpf(x); }
#define L2E 1.4426950408889634f
__device__ __forceinline__ float sigmoid_fast(float x){ return frcp(1.f + fexp2(-L2E*x)); }
__device__ __forceinline__ float tanh_fast(float x){ return 1.f - 2.f*frcp(1.f + fexp2((2.f*L2E)*x)); }

#if __has_builtin(__builtin_amdgcn_fdot2)
__device__ __forceinline__ float fdot2(h2v a, h2v b, float c){
  return __builtin_amdgcn_fdot2(a, b, c, false);
}
#else
__device__ __forceinline__ float fdot2(h2v a, h2v b, float c){
  return fmaf((float)a.x, (float)b.x, fmaf((float)a.y, (float)b.y, c));
}
#endif

__device__ __forceinline__ h2v bch2(float x){ return __builtin_bit_cast(h2v, x); }

__device__ __forceinline__ void loadarr32(float arr[32], const float* bufrow){
  const float4* p4 = (const float4*)bufrow;
  #pragma unroll
  for (int q4=0;q4<8;q4++){ float4 vv=p4[q4]; arr[4*q4]=vv.x; arr[4*q4+1]=vv.y; arr[4*q4+2]=vv.z; arr[4*q4+3]=vv.w; }
}

// ---------------------------------------------------------------------------
// Kernel 1: fused x-proj + LSTM recurrence + qkv projection.
// One wave per batch element. Lanes: half=lane>>5, j=lane&31.
//   half0,j<30: gates i[j] (acc0) and g[j] (acc1)
//   half1,j<30: gates f[j] (acc0) and o[j] (acc1)
// h state packed fp16 (half2 pairs) in LDS; recurrence via v_dot2_f32_f16.
//
// R5 synthesis: VGPR_Count=52 with zero scratch traffic == VGPR->AGPR file
// split (arch capped ~64) triggered by PRE-RA PRESSURE SPIKE in the weight
// prologue (60 f32 temps + 32 packed h2v + state ~130 live > budget).
// Fix (a): pack weights in 3-h2v chunks with asm memory barriers between
// chunks -> peak prologue pressure ~chunk-sized; one-time cost only.
// Fix (b): __launch_bounds__(128,2) -> 256-VGPR budget, spill impossible.
// 128-thr blocks (2 waves), grid 2048: 8 blocks/CU -> 16 waves/CU.
// ---------------------------------------------------------------------------
extern "C" __global__ void __launch_bounds__(128, 2)
lstm_k(const float* __restrict__ input, const float* __restrict__ w_ih,
       const float* __restrict__ w_hh, const float* __restrict__ b_ih,
       const float* __restrict__ b_hh, const float* __restrict__ in_proj_w,
       const float* __restrict__ in_proj_b,
       float* __restrict__ qo, float* __restrict__ ko, float* __restrict__ vo,
       float* __restrict__ ho)
{
  __shared__ __align__(16) float xbuf[2][320];  // 64-step input chunk per wave
  __shared__ __align__(16) float hp[2][16];     // h as 16 packed half2 (pair 15 = 0)
  const int wave = threadIdx.x >> 6;
  const int lane = threadIdx.x & 63;
  const int half = lane >> 5;
  const int j    = lane & 31;
  const int b    = blockIdx.x * 2 + wave;
  const bool act = (j < NE);
  const int g0 = half*NE + j;        // i- or f-row
  const int g1 = 60 + half*NE + j;   // g- or o-row

  // packed fp16 weight pairs (index 15 = zero pad)
  h2v wr0p[16], wr1p[16];
  float wi0[NIN], wi1[NIN];
  float bb0 = 0.f, bb1 = 0.f;
  #pragma unroll
  for (int k2=0;k2<16;k2++){ wr0p[k2]=(h2v)0; wr1p[k2]=(h2v)0; }
  #pragma unroll
  for (int m=0;m<NIN;m++){ wi0[m]=0.f; wi1[m]=0.f; }
  if (act) {
    // chunked pack: <=12 f32 temps live per chunk; barrier stops the
    // scheduler from hoisting all 60 loads together (the pressure spike
    // that triggered the VGPR/AGPR file split in R1-R5).
    #pragma unroll
    for (int cc=0; cc<5; ++cc) {
      #pragma unroll
      for (int u=0; u<3; ++u) {
        const int k2 = cc*3+u;
        h2v w0, w1;
        w0.x = (_Float16)w_hh[g0*NE+2*k2];   w0.y = (_Float16)w_hh[g0*NE+2*k2+1];
        w1.x = (_Float16)w_hh[g1*NE+2*k2];   w1.y = (_Float16)w_hh[g1*NE+2*k2+1];
        wr0p[k2]=w0; wr1p[k2]=w1;
      }
      asm volatile("" ::: "memory");
    }
    #pragma unroll
    for (int m=0;m<NIN;m++){ wi0[m]=w_ih[g0*NIN+m]; wi1[m]=w_ih[g1*NIN+m]; }
    bb0 = b_ih[g0]+b_hh[g0];
    bb1 = b_ih[g1]+b_hh[g1];
  }
  if (lane < 16) hp[wave][lane] = 0.f;   // zero-packed h (incl pad pair 15)
  float c = 0.f, hlast = 0.f;
  // half0 -> tanh via 2*sigmoid(2x)-1 ; half1 -> sigmoid(x)
  const float sMul = half ? -L2E : -2.f*L2E;   // folded sigmoid input scale
  const float aMul = half ? 1.f : 2.f;
  const float aAdd = half ? 0.f : -1.f;
  const float* xrow = input + (size_t)b * (Tlen*NIN);
  __builtin_amdgcn_wave_barrier();

  for (int tc = 0; tc < Tlen; tc += 64) {
    // stage 64 steps of input (320 floats) into LDS, coalesced
    #pragma unroll
    for (int r=0;r<5;r++) xbuf[wave][lane + 64*r] = xrow[tc*5 + lane + 64*r];
    __builtin_amdgcn_wave_barrier();
    #pragma unroll 1
    for (int tl=0; tl<64; ++tl) {
      const float x0 = xbuf[wave][tl*5+0], x1v = xbuf[wave][tl*5+1],
                  x2v = xbuf[wave][tl*5+2], x3v = xbuf[wave][tl*5+3],
                  x4v = xbuf[wave][tl*5+4];
      float a0a = bb0, a0b = 0.f, a1a = bb1, a1b = 0.f;
      a0a = fmaf(wi0[0],x0,a0a);  a1a = fmaf(wi1[0],x0,a1a);
      a0b = fmaf(wi0[1],x1v,a0b); a1b = fmaf(wi1[1],x1v,a1b);
      a0a = fmaf(wi0[2],x2v,a0a); a1a = fmaf(wi1[2],x2v,a1a);
      a0b = fmaf(wi0[3],x3v,a0b); a1b = fmaf(wi1[3],x3v,a1b);
      a0a = fmaf(wi0[4],x4v,a0a); a1a = fmaf(wi1[4],x4v,a1a);
      // h matvec: 16 packed pairs via 4x ds_read_b128, v_dot2_f32_f16
      const float4* hp4 = (const float4*)&hp[wave][0];
      #pragma unroll
      for (int q=0;q<4;q++){
        float4 hv = hp4[q];
        h2v h0=bch2(hv.x), h1=bch2(hv.y), hq2=bch2(hv.z), h3=bch2(hv.w);
        a0a = fdot2(wr0p[4*q+0], h0,  a0a);
        a0b = fdot2(wr0p[4*q+1], h1,  a0b);
        a1a = fdot2(wr1p[4*q+0], h0,  a1a);
        a1b = fdot2(wr1p[4*q+1], h1,  a1b);
        a0a = fdot2(wr0p[4*q+2], hq2, a0a);
        a0b = fdot2(wr0p[4*q+3], h3,  a0b);
        a1a = fdot2(wr1p[4*q+2], hq2, a1a);
        a1b = fdot2(wr1p[4*q+3], h3,  a1b);
      }
      const float ac0 = a0a + a0b;
      const float ac1 = a1a + a1b;
      const float s0 = sigmoid_fast(ac0);               // i (half0) or f (half1)
      const float ss = frcp(1.f + fexp2(sMul*ac1));
      const float go = fmaf(aMul, ss, aAdd);            // g (half0) or o (half1)
      const float o0 = __shfl_xor(s0, 32);
      const float o1 = __shfl_xor(go, 32);
      const float iv = half ? o0 : s0;
      const float fv = half ? s0 : o0;
      const float gv = half ? o1 : go;
      const float ov = half ? go : o1;
      c = fmaf(fv, c, iv*gv);
      const float hnew = ov * tanh_fast(c);
      hlast = hnew;
      const float hup = __shfl_xor(hnew, 1);            // partner for packing
      if (half==0 && act && !(j&1)) {
        h2v pk; pk.x = (_Float16)hnew; pk.y = (_Float16)hup;
        hp[wave][j>>1] = __builtin_bit_cast(float, pk);
      }
      __builtin_amdgcn_wave_barrier();
    }
  }

  // ---- tail: q = h@Wq^T+bq (pre-scaled by 1/sqrt(HD)); k,v from c ----
  float* cbuf = &xbuf[wave][0];     // c fp32, 32 slots zero-padded
  float* hb32 = &xbuf[wave][32];    // h fp32, 32 slots zero-padded
  if (half==0) { cbuf[lane] = act ? c : 0.f; hb32[lane] = act ? hlast : 0.f; }
  __builtin_amdgcn_wave_barrier();
  if (half==0 && act) ho[b*NE + j] = hlast;
  const float QS = 0.31622776601683794f;     // 1/sqrt(10)
  #pragma unroll
  for (int rep=0; rep<2; ++rep) {
    const int o = lane + rep*64;
    if (o < 90) {
      const float* wrow = in_proj_w + o*NE;
      const float* src  = (o < NE) ? hb32 : cbuf;
      float acc = in_proj_b[o];
      #pragma unroll
      for (int k2=0;k2<NE;k2++) acc = fmaf(wrow[k2], src[k2], acc);
      if (o < 30)      { qo[(o/10)*B10 + b*10 + (o%10)] = acc * QS; }
      else if (o < 60) { const int u=o-30; ko[(u/10)*B10 + b*10 + (u%10)] = acc; }
      else             { const int u=o-60; vo[(u/10)*B10 + b*10 + (u%10)] = acc; }
    }
  }
}

// ---------------------------------------------------------------------------
// Kernel 2a: flash attention partials. 1 thread = 1 query row.
// grid = (16 qblocks, 3 heads, NS ksplits), block = 256.
// K/V addresses are wave-uniform (blockIdx + loop counter) -> scalar/broadcast
// loads, zero per-lane traffic. NS=16 when ws_size allows -> 3072 waves
// (3/SIMD) for latency hiding; else NS=8.
// ---------------------------------------------------------------------------
extern "C" __global__ void __launch_bounds__(256)
attn_part(const float* __restrict__ q, const float* __restrict__ k,
          const float* __restrict__ v, float* __restrict__ part, int nkeys)
{
  const int t    = threadIdx.x;
  const int qr   = blockIdx.x*256 + t;
  const int head = blockIdx.y;
  const int ks   = blockIdx.z;
  const float* kh = k + (size_t)head*B10;
  const float* vh = v + (size_t)head*B10;
  float qreg[10];
  {
    const float2* qp = (const float2*)(q + (size_t)head*B10 + (size_t)qr*10);
    #pragma unroll
    for (int i=0;i<5;i++){ float2 t2=qp[i]; qreg[2*i]=t2.x; qreg[2*i+1]=t2.y; }
  }
  float m = -INFINITY, l = 0.f, acc[10];
  #pragma unroll
  for (int d=0;d<10;d++) acc[d]=0.f;

  const int k0 = ks * nkeys;
  #pragma unroll 1
  for (int cch=0; cch<nkeys; cch+=8) {
    const int kb = k0 + cch;           // wave-uniform
    float s[8];
    #pragma unroll
    for (int u=0;u<8;u++){
      const float* kp = kh + (size_t)(kb+u)*10;
      float sv = 0.f;
      #pragma unroll
      for (int i=0;i<10;i++) sv = fmaf(qreg[i], kp[i], sv);
      s[u]=sv;
    }
    float mc = s[0];
    #pragma unroll
    for (int u=1;u<8;u++) mc = fmaxf(mc, s[u]);
    const float mnew = fmaxf(m, mc);
    const float corr = fexp2(L2E*(m - mnew));   // m=-inf first chunk -> 0
    l *= corr;
    #pragma unroll
    for (int d=0;d<10;d++) acc[d]*=corr;
    #pragma unroll
    for (int u=0;u<8;u++){
      const float p = fexp2(L2E*(s[u]-mnew));
      l += p;
      const float* vp = vh + (size_t)(kb+u)*10;
      #pragma unroll
      for (int d=0;d<10;d++) acc[d] = fmaf(p, vp[d], acc[d]);
    }
    m = mnew;
  }
  float* pp = part + ((size_t)(head*Bsz + qr)*gridDim.z + ks)*12;
  pp[0]=m; pp[1]=l;
  #pragma unroll
  for (int d=0;d<10;d++) pp[2+d]=acc[d];
}

// ---------------------------------------------------------------------------
// Kernel 2b: merge ns partials per (head, query) -> ctx.
// 12288 threads, one per (head, query).
// ---------------------------------------------------------------------------
extern "C" __global__ void __launch_bounds__(256)
attn_merge(const float* __restrict__ part, float* __restrict__ ctx, int ns)
{
  const int id = blockIdx.x*256 + threadIdx.x;   // 0..12287
  const int head = id >> 12;
  const int qr   = id & 4095;
  const float* p = part + (size_t)id*ns*12;
  float M = p[0];
  for (int i=1;i<ns;i++) M = fmaxf(M, p[i*12]);
  float L=0.f, o[10];
  #pragma unroll
  for (int d=0;d<10;d++) o[d]=0.f;
  for (int i=0;i<ns;i++){
    const float w = fexp2(L2E*(p[i*12]-M));
    L = fmaf(p[i*12+1], w, L);
    #pragma unroll
    for (int d=0;d<10;d++) o[d]=fmaf(p[i*12+2+d],w,o[d]);
  }
  const float invL = 1.f/L;
  float* cp = ctx + (size_t)head*B10 + (size_t)qr*10;
  #pragma unroll
  for (int d=0;d<10;d++) cp[d]=o[d]*invL;
}

// ---------------------------------------------------------------------------
// Kernel 3: out_proj + residual + LN + MLP(exact GELU) + LN + head.
// One wave per row; row vector staged in a per-wave 32-float LDS buffer.
// ---------------------------------------------------------------------------
extern "C" __global__ void __launch_bounds__(256)
tail_k(const float* __restrict__ ctx, const float* __restrict__ hn,
       const float* __restrict__ out_proj_w, const float* __restrict__ out_proj_b,
       const float* __restrict__ fc1_w, const float* __restrict__ fc1_b,
       const float* __restrict__ fc2_w, const float* __restrict__ fc2_b,
       const float* __restrict__ ln_g, const float* __restrict__ ln_b,
       const float* __restrict__ out_w, const float* __restrict__ out_b,
       float* __restrict__ out)
{
  __shared__ __align__(16) float buf[4][32];
  const int wave = threadIdx.x >> 6;
  const int lane = threadIdx.x & 63;
  const int b = blockIdx.x*4 + wave;
  const bool act = (lane < NE);
  if (lane < 32) buf[wave][lane] = 0.f;
  __builtin_amdgcn_wave_barrier();
  if (act) buf[wave][lane] = ctx[(lane/10)*B10 + b*10 + (lane%10)];
  __builtin_amdgcn_wave_barrier();
  float arr[32];
  loadarr32(arr, &buf[wave][0]);
  const float hv = act ? hn[b*NE+lane] : 0.f;
  float x = 0.f;
  if (act) {
    float a = out_proj_b[lane];
    #pragma unroll
    for (int k2=0;k2<NE;k2++) a = fmaf(out_proj_w[lane*NE+k2], arr[k2], a);
    x = a + hv;                       // attn_out + h_n
  }
  // LN1
  __builtin_amdgcn_wave_barrier();
  if (act) buf[wave][lane] = x;
  __builtin_amdgcn_wave_barrier();
  loadarr32(arr, &buf[wave][0]);
  float s1=0.f, s2=0.f;
  #pragma unroll
  for (int k2=0;k2<32;k2++){ s1+=arr[k2]; s2=fmaf(arr[k2],arr[k2],s2); }
  float mu = s1*(1.f/30.f);
  float var = s2*(1.f/30.f) - mu*mu;
  float rs = rsqrtf(var + 1e-5f);
  float x1 = 0.f;
  if (act) x1 = fmaf((x-mu)*rs, ln_g[lane], ln_b[lane]);
  // fc1 + exact GELU
  __builtin_amdgcn_wave_barrier();
  if (act) buf[wave][lane] = x1;
  __builtin_amdgcn_wave_barrier();
  loadarr32(arr, &buf[wave][0]);
  float gv = 0.f;
  if (act) {
    float a = fc1_b[lane];
    #pragma unroll
    for (int k2=0;k2<NE;k2++) a = fmaf(fc1_w[lane*NE+k2], arr[k2], a);
    gv = 0.5f*a*(1.f + erff(a*0.70710678118654752f));
  }
  // fc2
  __builtin_amdgcn_wave_barrier();
  if (act) buf[wave][lane] = gv;
  __builtin_amdgcn_wave_barrier();
  loadarr32(arr, &buf[wave][0]);
  float y = 0.f;
  if (act) {
    float a = fc2_b[lane];
    #pragma unroll
    for (int k2=0;k2<NE;k2++) a = fmaf(fc2_w[lane*NE+k2], arr[k2], a);
    y = x1 + a;                        // residual x1 + fc
  }
  // LN2
  __builtin_amdgcn_wave_barrier();
  if (act) buf[wave][lane] = y;
  __builtin_amdgcn_wave_barrier();
  loadarr32(arr, &buf[wave][0]);
  s1=0.f; s2=0.f;
  #pragma unroll
  for (int k2=0;k2<32;k2++){ s1+=arr[k2]; s2=fmaf(arr[k2],arr[k2],s2); }
  mu = s1*(1.f/30.f);
  var = s2*(1.f/30.f) - mu*mu;
  rs = rsqrtf(var + 1e-5f);
  float x2 = 0.f;
  if (act) x2 = fmaf((y-mu)*rs, ln_g[lane], ln_b[lane]);
  // head: [3,30]
  __builtin_amdgcn_wave_barrier();
  if (act) buf[wave][lane] = x2;
  __builtin_amdgcn_wave_barrier();
  loadarr32(arr, &buf[wave][0]);
  if (lane < 3) {
    float a = out_b[lane];
    #pragma unroll
    for (int k2=0;k2<NE;k2++) a = fmaf(out_w[lane*NE+k2], arr[k2], a);
    out[b*3 + lane] = a;
  }
}

extern "C" void kernel_launch(void* const* d_in, const int* in_sizes, int n_in,
                              void* d_out, int out_size, void* d_ws, size_t ws_size,
                              hipStream_t stream)
{
  const float* input      = (const float*)d_in[0];
  const float* w_ih       = (const float*)d_in[1];
  const float* w_hh       = (const float*)d_in[2];
  const float* b_ih       = (const float*)d_in[3];
  const float* b_hh       = (const float*)d_in[4];
  const float* in_proj_w  = (const float*)d_in[5];
  const float* in_proj_b  = (const float*)d_in[6];
  const float* out_proj_w = (const float*)d_in[7];
  const float* out_proj_b = (const float*)d_in[8];
  const float* fc1_w      = (const float*)d_in[9];
  const float* fc1_b      = (const float*)d_in[10];
  const float* fc2_w      = (const float*)d_in[11];
  const float* fc2_b      = (const float*)d_in[12];
  const float* ln_g       = (const float*)d_in[13];
  const float* ln_b       = (const float*)d_in[14];
  const float* out_w      = (const float*)d_in[15];
  const float* out_b      = (const float*)d_in[16];

  float* ws = (float*)d_ws;
  float* qo   = ws;                 // [3][4096][10]
  float* ko   = ws + 122880;        // [3][4096][10]
  float* vo   = ws + 245760;        // [3][4096][10]
  float* hn   = ws + 368640;        // [4096][30]
  float* cx   = ws + 491520;        // [3][4096][10]
  float* part = ws + 614400;        // [3][4096][NS][12]

  // NS=16 needs (614400 + 3*4096*16*12)*4 B = ~11.9 MB of ws. ws_size is
  // fixed across calls -> choice is deterministic (graph-capture safe).
  const size_t need16 = ((size_t)614400 + (size_t)3*4096*16*12) * 4;
  const int NS = (ws_size >= need16) ? 16 : 8;

  lstm_k<<<Bsz/2, 128, 0, stream>>>(input, w_ih, w_hh, b_ih, b_hh,
                                    in_proj_w, in_proj_b, qo, ko, vo, hn);
  attn_part<<<dim3(Bsz/256, 3, NS), 256, 0, stream>>>(qo, ko, vo, part, Bsz/NS);
  attn_merge<<<(3*Bsz)/256, 256, 0, stream>>>(part, cx, NS);
  tail_k<<<Bsz/4, 256, 0, stream>>>(cx, hn, out_proj_w, out_proj_b,
                                    fc1_w, fc1_b, fc2_w, fc2_b,
                                    ln_g, ln_b, out_w, out_b, (float*)d_out);
}

// Round 7
// 430.734 us; speedup vs baseline: 3.4452x; 1.1484x over previous
//
#include <hip/hip_runtime.h>
#include <math.h>

// Problem constants
#define Bsz  4096
#define Tlen 512
#define NE   30
#define NIN  5
#define HD10 10
#define B10  (Bsz*HD10)   // per-head plane: 40960 floats

typedef _Float16 h2v  __attribute__((ext_vector_type(2)));
typedef _Float16 f16x8 __attribute__((ext_vector_type(8)));
typedef float    f32x4 __attribute__((ext_vector_type(4)));

__device__ __forceinline__ float fexp2(float x){ return __builtin_amdgcn_exp2f(x); }
__device__ __forceinline__ float frcp (float x){ return __builtin_amdgcn_rcpf(x); }
#define L2E 1.4426950408889634f
__device__ __forceinline__ float sigmoid_fast(float x){ return frcp(1.f + fexp2(-L2E*x)); }
__device__ __forceinline__ float tanh_fast(float x){ return 1.f - 2.f*frcp(1.f + fexp2((2.f*L2E)*x)); }

__device__ __forceinline__ void loadarr32(float arr[32], const float* bufrow){
  const float4* p4 = (const float4*)bufrow;
  #pragma unroll
  for (int q4=0;q4<8;q4++){ float4 vv=p4[q4]; arr[4*q4]=vv.x; arr[4*q4+1]=vv.y; arr[4*q4+2]=vv.z; arr[4*q4+3]=vv.w; }
}

// ---------------------------------------------------------------------------
// Kernel 1 (MFMA rewrite): fused x-proj + LSTM recurrence + qkv projection.
// One block (128 thr, 2 waves) per 16-batch group; grid 256.
// Gate matrix padded to Wpad[128][32]: gate G (i,f,g,o) occupies rows
// 32G..32G+29 (pad rows/cols zero). Wave w owns rows 32G+16w..+15 of each
// gate: 4 A-frags (h-part, K=0..31=h-dim) + 4 A-frags (x-part, K=0..4=x) +
// 4 fp32x4 bias C-init frags. Per step:
//   C_G = mfma(ax_G, bx, bias_G); C_G = mfma(ah_G, bh, C_G)   (8 MFMAs)
// then per-lane activations for 4 dims x 4 gates, c-state in 4 VGPRs,
// h packed fp16 -> double-buffered LDS [16 batches][40 halves], 1 barrier/step.
// WHY MFMA: R1-R6 showed the RA demotes big VALU-read weight arrays to AGPRs
// (VGPR_Count 40-52, ~90 accvgpr copies/step, 4 failed counter-measures).
// MFMA reads A/B/C operands from AGPRs natively -> demotion becomes free.
// Fragment layouts (cdna_hip_programming.md, m89/m120-verified):
//   A[m=lane&15][k=(lane>>4)*8+j], B[k=(lane>>4)*8+j][n=lane&15],
//   D[m=(lane>>4)*4+r][n=lane&15].
// ---------------------------------------------------------------------------
extern "C" __global__ void __launch_bounds__(128)
lstm_k(const float* __restrict__ input, const float* __restrict__ w_ih,
       const float* __restrict__ w_hh, const float* __restrict__ b_ih,
       const float* __restrict__ b_hh, const float* __restrict__ in_proj_w,
       const float* __restrict__ in_proj_b,
       float* __restrict__ qo, float* __restrict__ ko, float* __restrict__ vo,
       float* __restrict__ ho)
{
  __shared__ __align__(16) _Float16 hbufh[2*16*40];  // [parity][n][k] 2560 B
  __shared__ __align__(16) float    xstf[16*324];    // x stage / hf+cf reuse
  const int tidb = threadIdx.x;
  const int wave = tidb >> 6;
  const int lane = tidb & 63;
  const int n    = lane & 15;        // batch within group (B-frag/D col)
  const int quad = lane >> 4;
  const int b0   = blockIdx.x * 16;

  // ---- build A-frags + bias C-init (once) ----
  const int mrow = 16*wave + n;            // dim within gate for A rows
  const bool rv  = (mrow < NE);
  f16x8 ah[4], ax[4];
  f32x4 bi[4];
  #pragma unroll
  for (int G=0; G<4; ++G){
    const int grow = rv ? (NE*G + mrow) : 0;
    #pragma unroll
    for (int j=0;j<8;++j){
      const int k = quad*8 + j;
      ah[G][j] = (rv && k < NE) ? (_Float16)w_hh[grow*NE + k] : (_Float16)0;
      ax[G][j] = (rv && quad==0 && j < NIN) ? (_Float16)w_ih[grow*NIN + j] : (_Float16)0;
    }
    #pragma unroll
    for (int r=0;r<4;++r){
      const int d = 16*wave + quad*4 + r;  // D row -> dim
      const int gr = (d < NE) ? (NE*G + d) : 0;
      bi[G][r] = (d < NE) ? (b_ih[gr] + b_hh[gr]) : 0.f;
    }
  }
  // zero h double-buffer
  for (int i=tidb; i<640; i+=128) ((float*)hbufh)[i] = 0.f;

  float c0=0.f,c1=0.f,c2=0.f,c3=0.f;
  float h0f=0.f,h1f=0.f,h2f=0.f,h3f=0.f;
  const int xb = n*324;
  const int hb = n*40 + quad*8;            // bh read offset (halves)
  const int hw = n*40 + 16*wave + 4*quad;  // h write offset (halves)
  const bool q0 = (quad == 0);
  const f16x8 zf8 = (f16x8)(_Float16)0;

  for (int tc = 0; tc < Tlen; tc += 64) {
    // stage 64 steps x 16 batches x 5 inputs (float4, coalesced)
    for (int i4 = tidb; i4 < 1280; i4 += 128){
      const int nn = i4/80, o4 = (i4%80)*4;
      const float4 vv = *(const float4*)(input + (size_t)(b0+nn)*(Tlen*NIN) + tc*NIN + o4);
      *(float4*)(&xstf[nn*324 + o4]) = vv;
    }
    __syncthreads();
    #pragma unroll 1
    for (int tl2 = 0; tl2 < 32; ++tl2) {
      #pragma unroll
      for (int par=0; par<2; ++par) {
        const int tl = 2*tl2 + par;
        const _Float16* rbuf = hbufh + par*640;
        _Float16*       wbuf = hbufh + (par^1)*640;
        // B-frag (x-part): quad0 lanes carry [x0..x4,0,0,0]
        const float xv0 = xstf[xb + tl*5+0], xv1 = xstf[xb + tl*5+1],
                    xv2 = xstf[xb + tl*5+2], xv3 = xstf[xb + tl*5+3],
                    xv4 = xstf[xb + tl*5+4];
        union { f16x8 v; h2v h[4]; } U;
        U.h[0].x=(_Float16)xv0; U.h[0].y=(_Float16)xv1;
        U.h[1].x=(_Float16)xv2; U.h[1].y=(_Float16)xv3;
        U.h[2].x=(_Float16)xv4; U.h[2].y=(_Float16)0;
        U.h[3]=(h2v)0;
        const f16x8 bx = q0 ? U.v : zf8;
        // B-frag (h-part)
        const f16x8 bh = *(const f16x8*)(rbuf + hb);
        // 8 MFMAs: gates i,f,g,o
        f32x4 Ci = __builtin_amdgcn_mfma_f32_16x16x32_f16(ax[0], bx, bi[0], 0,0,0);
        f32x4 Cf = __builtin_amdgcn_mfma_f32_16x16x32_f16(ax[1], bx, bi[1], 0,0,0);
        f32x4 Cg = __builtin_amdgcn_mfma_f32_16x16x32_f16(ax[2], bx, bi[2], 0,0,0);
        f32x4 Co = __builtin_amdgcn_mfma_f32_16x16x32_f16(ax[3], bx, bi[3], 0,0,0);
        Ci = __builtin_amdgcn_mfma_f32_16x16x32_f16(ah[0], bh, Ci, 0,0,0);
        Cf = __builtin_amdgcn_mfma_f32_16x16x32_f16(ah[1], bh, Cf, 0,0,0);
        Cg = __builtin_amdgcn_mfma_f32_16x16x32_f16(ah[2], bh, Cg, 0,0,0);
        Co = __builtin_amdgcn_mfma_f32_16x16x32_f16(ah[3], bh, Co, 0,0,0);
        // activations (4 dims/lane); invalid pad dims -> preact 0 -> h stays 0
        {
          const float iv=sigmoid_fast(Ci[0]), fv=sigmoid_fast(Cf[0]),
                      gv=tanh_fast(Cg[0]),    ov=sigmoid_fast(Co[0]);
          c0 = fmaf(fv, c0, iv*gv); h0f = ov * tanh_fast(c0);
        }
        {
          const float iv=sigmoid_fast(Ci[1]), fv=sigmoid_fast(Cf[1]),
                      gv=tanh_fast(Cg[1]),    ov=sigmoid_fast(Co[1]);
          c1 = fmaf(fv, c1, iv*gv); h1f = ov * tanh_fast(c1);
        }
        {
          const float iv=sigmoid_fast(Ci[2]), fv=sigmoid_fast(Cf[2]),
                      gv=tanh_fast(Cg[2]),    ov=sigmoid_fast(Co[2]);
          c2 = fmaf(fv, c2, iv*gv); h2f = ov * tanh_fast(c2);
        }
        {
          const float iv=sigmoid_fast(Ci[3]), fv=sigmoid_fast(Cf[3]),
                      gv=tanh_fast(Cg[3]),    ov=sigmoid_fast(Co[3]);
          c3 = fmaf(fv, c3, iv*gv); h3f = ov * tanh_fast(c3);
        }
        // pack h -> fp16, write 4 contiguous dims (8B)
        h2v q01, q23;
        q01.x=(_Float16)h0f; q01.y=(_Float16)h1f;
        q23.x=(_Float16)h2f; q23.y=(_Float16)h3f;
        float2 wv;
        wv.x = __builtin_bit_cast(float, q01);
        wv.y = __builtin_bit_cast(float, q23);
        *(float2*)(wbuf + hw) = wv;
        __syncthreads();
      }
    }
  }

  // ---- tail: stash fp32 h,c; project q(h), k(c), v(c) ----
  float* hf = xstf;            // [16][36]
  float* cf = xstf + 16*36;
  {
    const int d0 = 16*wave + 4*quad;
    float4 hv4; hv4.x=h0f; hv4.y=h1f; hv4.z=h2f; hv4.w=h3f;
    float4 cv4; cv4.x=c0;  cv4.y=c1;  cv4.z=c2;  cv4.w=c3;
    *(float4*)(&hf[n*36 + d0]) = hv4;
    *(float4*)(&cf[n*36 + d0]) = cv4;
  }
  __syncthreads();
  for (int i = tidb; i < 16*NE; i += 128){
    const int nn = i/NE, d = i%NE;
    ho[(size_t)(b0+nn)*NE + d] = hf[nn*36 + d];
  }
  const float QS = 0.31622776601683794f;     // 1/sqrt(10)
  for (int i = tidb; i < 90*16; i += 128){
    const int o  = i % 90;
    const int nn = i / 90;
    const float* wrow = in_proj_w + o*NE;
    const float* src  = (o < NE) ? &hf[nn*36] : &cf[nn*36];
    float acc = in_proj_b[o];
    #pragma unroll
    for (int k2=0;k2<NE;k2++) acc = fmaf(wrow[k2], src[k2], acc);
    const int b = b0 + nn;
    if (o < 30)      { qo[(o/10)*B10 + b*10 + (o%10)] = acc * QS; }
    else if (o < 60) { const int u=o-30; ko[(u/10)*B10 + b*10 + (u%10)] = acc; }
    else             { const int u=o-60; vo[(u/10)*B10 + b*10 + (u%10)] = acc; }
  }
}

// ---------------------------------------------------------------------------
// Kernel 2a: flash attention partials. 1 thread = 1 query row. (unchanged R6)
// ---------------------------------------------------------------------------
extern "C" __global__ void __launch_bounds__(256)
attn_part(const float* __restrict__ q, const float* __restrict__ k,
          const float* __restrict__ v, float* __restrict__ part, int nkeys)
{
  const int t    = threadIdx.x;
  const int qr   = blockIdx.x*256 + t;
  const int head = blockIdx.y;
  const int ks   = blockIdx.z;
  const float* kh = k + (size_t)head*B10;
  const float* vh = v + (size_t)head*B10;
  float qreg[10];
  {
    const float2* qp = (const float2*)(q + (size_t)head*B10 + (size_t)qr*10);
    #pragma unroll
    for (int i=0;i<5;i++){ float2 t2=qp[i]; qreg[2*i]=t2.x; qreg[2*i+1]=t2.y; }
  }
  float m = -INFINITY, l = 0.f, acc[10];
  #pragma unroll
  for (int d=0;d<10;d++) acc[d]=0.f;

  const int k0 = ks * nkeys;
  #pragma unroll 1
  for (int cch=0; cch<nkeys; cch+=8) {
    const int kb = k0 + cch;           // wave-uniform
    float s[8];
    #pragma unroll
    for (int u=0;u<8;u++){
      const float* kp = kh + (size_t)(kb+u)*10;
      float sv = 0.f;
      #pragma unroll
      for (int i=0;i<10;i++) sv = fmaf(qreg[i], kp[i], sv);
      s[u]=sv;
    }
    float mc = s[0];
    #pragma unroll
    for (int u=1;u<8;u++) mc = fmaxf(mc, s[u]);
    const float mnew = fmaxf(m, mc);
    const float corr = fexp2(L2E*(m - mnew));   // m=-inf first chunk -> 0
    l *= corr;
    #pragma unroll
    for (int d=0;d<10;d++) acc[d]*=corr;
    #pragma unroll
    for (int u=0;u<8;u++){
      const float p = fexp2(L2E*(s[u]-mnew));
      l += p;
      const float* vp = vh + (size_t)(kb+u)*10;
      #pragma unroll
      for (int d=0;d<10;d++) acc[d] = fmaf(p, vp[d], acc[d]);
    }
    m = mnew;
  }
  float* pp = part + ((size_t)(head*Bsz + qr)*gridDim.z + ks)*12;
  pp[0]=m; pp[1]=l;
  #pragma unroll
  for (int d=0;d<10;d++) pp[2+d]=acc[d];
}

// ---------------------------------------------------------------------------
// Kernel 2b: merge ns partials per (head, query) -> ctx. (unchanged R6)
// ---------------------------------------------------------------------------
extern "C" __global__ void __launch_bounds__(256)
attn_merge(const float* __restrict__ part, float* __restrict__ ctx, int ns)
{
  const int id = blockIdx.x*256 + threadIdx.x;   // 0..12287
  const int head = id >> 12;
  const int qr   = id & 4095;
  const float* p = part + (size_t)id*ns*12;
  float M = p[0];
  for (int i=1;i<ns;i++) M = fmaxf(M, p[i*12]);
  float L=0.f, o[10];
  #pragma unroll
  for (int d=0;d<10;d++) o[d]=0.f;
  for (int i=0;i<ns;i++){
    const float w = fexp2(L2E*(p[i*12]-M));
    L = fmaf(p[i*12+1], w, L);
    #pragma unroll
    for (int d=0;d<10;d++) o[d]=fmaf(p[i*12+2+d],w,o[d]);
  }
  const float invL = 1.f/L;
  float* cp = ctx + (size_t)head*B10 + (size_t)qr*10;
  #pragma unroll
  for (int d=0;d<10;d++) cp[d]=o[d]*invL;
}

// ---------------------------------------------------------------------------
// Kernel 3: out_proj + residual + LN + MLP(exact GELU) + LN + head. (unchanged)
// ---------------------------------------------------------------------------
extern "C" __global__ void __launch_bounds__(256)
tail_k(const float* __restrict__ ctx, const float* __restrict__ hn,
       const float* __restrict__ out_proj_w, const float* __restrict__ out_proj_b,
       const float* __restrict__ fc1_w, const float* __restrict__ fc1_b,
       const float* __restrict__ fc2_w, const float* __restrict__ fc2_b,
       const float* __restrict__ ln_g, const float* __restrict__ ln_b,
       const float* __restrict__ out_w, const float* __restrict__ out_b,
       float* __restrict__ out)
{
  __shared__ __align__(16) float buf[4][32];
  const int wave = threadIdx.x >> 6;
  const int lane = threadIdx.x & 63;
  const int b = blockIdx.x*4 + wave;
  const bool act = (lane < NE);
  if (lane < 32) buf[wave][lane] = 0.f;
  __builtin_amdgcn_wave_barrier();
  if (act) buf[wave][lane] = ctx[(lane/10)*B10 + b*10 + (lane%10)];
  __builtin_amdgcn_wave_barrier();
  float arr[32];
  loadarr32(arr, &buf[wave][0]);
  const float hv = act ? hn[b*NE+lane] : 0.f;
  float x = 0.f;
  if (act) {
    float a = out_proj_b[lane];
    #pragma unroll
    for (int k2=0;k2<NE;k2++) a = fmaf(out_proj_w[lane*NE+k2], arr[k2], a);
    x = a + hv;                       // attn_out + h_n
  }
  // LN1
  __builtin_amdgcn_wave_barrier();
  if (act) buf[wave][lane] = x;
  __builtin_amdgcn_wave_barrier();
  loadarr32(arr, &buf[wave][0]);
  float s1=0.f, s2=0.f;
  #pragma unroll
  for (int k2=0;k2<32;k2++){ s1+=arr[k2]; s2=fmaf(arr[k2],arr[k2],s2); }
  float mu = s1*(1.f/30.f);
  float var = s2*(1.f/30.f) - mu*mu;
  float rs = rsqrtf(var + 1e-5f);
  float x1 = 0.f;
  if (act) x1 = fmaf((x-mu)*rs, ln_g[lane], ln_b[lane]);
  // fc1 + exact GELU
  __builtin_amdgcn_wave_barrier();
  if (act) buf[wave][lane] = x1;
  __builtin_amdgcn_wave_barrier();
  loadarr32(arr, &buf[wave][0]);
  float gv = 0.f;
  if (act) {
    float a = fc1_b[lane];
    #pragma unroll
    for (int k2=0;k2<NE;k2++) a = fmaf(fc1_w[lane*NE+k2], arr[k2], a);
    gv = 0.5f*a*(1.f + erff(a*0.70710678118654752f));
  }
  // fc2
  __builtin_amdgcn_wave_barrier();
  if (act) buf[wave][lane] = gv;
  __builtin_amdgcn_wave_barrier();
  loadarr32(arr, &buf[wave][0]);
  float y = 0.f;
  if (act) {
    float a = fc2_b[lane];
    #pragma unroll
    for (int k2=0;k2<NE;k2++) a = fmaf(fc2_w[lane*NE+k2], arr[k2], a);
    y = x1 + a;                        // residual x1 + fc
  }
  // LN2
  __builtin_amdgcn_wave_barrier();
  if (act) buf[wave][lane] = y;
  __builtin_amdgcn_wave_barrier();
  loadarr32(arr, &buf[wave][0]);
  s1=0.f; s2=0.f;
  #pragma unroll
  for (int k2=0;k2<32;k2++){ s1+=arr[k2]; s2=fmaf(arr[k2],arr[k2],s2); }
  mu = s1*(1.f/30.f);
  var = s2*(1.f/30.f) - mu*mu;
  rs = rsqrtf(var + 1e-5f);
  float x2 = 0.f;
  if (act) x2 = fmaf((y-mu)*rs, ln_g[lane], ln_b[lane]);
  // head: [3,30]
  __builtin_amdgcn_wave_barrier();
  if (act) buf[wave][lane] = x2;
  __builtin_amdgcn_wave_barrier();
  loadarr32(arr, &buf[wave][0]);
  if (lane < 3) {
    float a = out_b[lane];
    #pragma unroll
    for (int k2=0;k2<NE;k2++) a = fmaf(out_w[lane*NE+k2], arr[k2], a);
    out[b*3 + lane] = a;
  }
}

extern "C" void kernel_launch(void* const* d_in, const int* in_sizes, int n_in,
                              void* d_out, int out_size, void* d_ws, size_t ws_size,
                              hipStream_t stream)
{
  const float* input      = (const float*)d_in[0];
  const float* w_ih       = (const float*)d_in[1];
  const float* w_hh       = (const float*)d_in[2];
  const float* b_ih       = (const float*)d_in[3];
  const float* b_hh       = (const float*)d_in[4];
  const float* in_proj_w  = (const float*)d_in[5];
  const float* in_proj_b  = (const float*)d_in[6];
  const float* out_proj_w = (const float*)d_in[7];
  const float* out_proj_b = (const float*)d_in[8];
  const float* fc1_w      = (const float*)d_in[9];
  const float* fc1_b      = (const float*)d_in[10];
  const float* fc2_w      = (const float*)d_in[11];
  const float* fc2_b      = (const float*)d_in[12];
  const float* ln_g       = (const float*)d_in[13];
  const float* ln_b       = (const float*)d_in[14];
  const float* out_w      = (const float*)d_in[15];
  const float* out_b      = (const float*)d_in[16];

  float* ws = (float*)d_ws;
  float* qo   = ws;                 // [3][4096][10]
  float* ko   = ws + 122880;        // [3][4096][10]
  float* vo   = ws + 245760;        // [3][4096][10]
  float* hn   = ws + 368640;        // [4096][30]
  float* cx   = ws + 491520;        // [3][4096][10]
  float* part = ws + 614400;        // [3][4096][NS][12]

  const size_t need16 = ((size_t)614400 + (size_t)3*4096*16*12) * 4;
  const int NS = (ws_size >= need16) ? 16 : 8;

  lstm_k<<<Bsz/16, 128, 0, stream>>>(input, w_ih, w_hh, b_ih, b_hh,
                                     in_proj_w, in_proj_b, qo, ko, vo, hn);
  attn_part<<<dim3(Bsz/256, 3, NS), 256, 0, stream>>>(qo, ko, vo, part, Bsz/NS);
  attn_merge<<<(3*Bsz)/256, 256, 0, stream>>>(part, cx, NS);
  tail_k<<<Bsz/4, 256, 0, stream>>>(cx, hn, out_proj_w, out_proj_b,
                                    fc1_w, fc1_b, fc2_w, fc2_b,
                                    ln_g, ln_b, out_w, out_b, (float*)d_out);
}

// Round 8
// 421.739 us; speedup vs baseline: 3.5187x; 1.0213x over previous
//
#include <hip/hip_runtime.h>
#include <math.h>

// Problem constants
#define Bsz  4096
#define Tlen 512
#define NE   30
#define NIN  5
#define HD10 10
#define B10  (Bsz*HD10)   // per-head plane: 40960 floats

typedef _Float16 h2v  __attribute__((ext_vector_type(2)));
typedef _Float16 f16x8 __attribute__((ext_vector_type(8)));
typedef float    f32x4 __attribute__((ext_vector_type(4)));

__device__ __forceinline__ float fexp2(float x){ return __builtin_amdgcn_exp2f(x); }
__device__ __forceinline__ float frcp (float x){ return __builtin_amdgcn_rcpf(x); }
#define L2E 1.4426950408889634f
__device__ __forceinline__ float sigmoid_fast(float x){ return frcp(1.f + fexp2(-L2E*x)); }

__device__ __forceinline__ void loadarr32(float arr[32], const float* bufrow){
  const float4* p4 = (const float4*)bufrow;
  #pragma unroll
  for (int q4=0;q4<8;q4++){ float4 vv=p4[q4]; arr[4*q4]=vv.x; arr[4*q4+1]=vv.y; arr[4*q4+2]=vv.z; arr[4*q4+3]=vv.w; }
}

// ---------------------------------------------------------------------------
// Kernel 1 (MFMA LSTM, R8 serial-path tuning): fused x-proj + recurrence + qkv.
// One block (128 thr, 2 waves) per 16-batch group; grid 256 (1 block/CU).
// R7 analysis: 1275 cyc/step = ~440 irreducible activation VALU + ~835
// exposed latency (1 wave/SIMD hides nothing). R8 attacks the 835:
//  - x reads for BOTH half-steps hoisted to tl2-top (latency under compute)
//  - x repacked [n][t][6] stride-390 dwords -> 3x ds_read_b64, no bank clash
//  - activation input scales (-L2E / -2L2E) folded into A-frags + bias:
//    MFMA delivers pre-scaled preacts, sigmoid/tanh lose their input mul
//  - bh read issued before ax-MFMAs so its ~120cyc overlaps their issue
// Fragment layouts (m89/m120-verified, R7-proven):
//   A[m=lane&15][k=(lane>>4)*8+j], B[k=(lane>>4)*8+j][n=lane&15],
//   D[m=(lane>>4)*4+r][n=lane&15].
// ---------------------------------------------------------------------------
extern "C" __global__ void __launch_bounds__(128)
lstm_k(const float* __restrict__ input, const float* __restrict__ w_ih,
       const float* __restrict__ w_hh, const float* __restrict__ b_ih,
       const float* __restrict__ b_hh, const float* __restrict__ in_proj_w,
       const float* __restrict__ in_proj_b,
       float* __restrict__ qo, float* __restrict__ ko, float* __restrict__ vo,
       float* __restrict__ ho)
{
  __shared__ __align__(16) _Float16 hbufh[2*16*40];  // [parity][n][k] 2560 B
  __shared__ __align__(16) float    xstf[16*390];    // x: [n][t][6pad] stride 390 dw
  const int tidb = threadIdx.x;
  const int wave = tidb >> 6;
  const int lane = tidb & 63;
  const int n    = lane & 15;        // batch within group (B-frag/D col)
  const int quad = lane >> 4;
  const int b0   = blockIdx.x * 16;

  // ---- build A-frags + bias C-init (once), activation scale folded in ----
  const int mrow = 16*wave + n;            // dim within gate for A rows
  const bool rv  = (mrow < NE);
  f16x8 ah[4], ax[4];
  f32x4 bi[4];
  #pragma unroll
  for (int G=0; G<4; ++G){
    const float sG = (G==2) ? (-2.f*L2E) : (-L2E);   // g gate: tanh via 2sig(2x)-1
    const int grow = rv ? (NE*G + mrow) : 0;
    #pragma unroll
    for (int j=0;j<8;++j){
      const int k = quad*8 + j;
      ah[G][j] = (rv && k < NE) ? (_Float16)(sG*w_hh[grow*NE + k]) : (_Float16)0;
      ax[G][j] = (rv && quad==0 && j < NIN) ? (_Float16)(sG*w_ih[grow*NIN + j]) : (_Float16)0;
    }
    #pragma unroll
    for (int r=0;r<4;++r){
      const int d = 16*wave + quad*4 + r;  // D row -> dim
      const int gr = (d < NE) ? (NE*G + d) : 0;
      bi[G][r] = (d < NE) ? sG*(b_ih[gr] + b_hh[gr]) : 0.f;
    }
  }
  // zero h double-buffer
  for (int i=tidb; i<640; i+=128) ((float*)hbufh)[i] = 0.f;

  float c0=0.f,c1=0.f,c2=0.f,c3=0.f;
  float h0f=0.f,h1f=0.f,h2f=0.f,h3f=0.f;
  const int hb = n*40 + quad*8;            // bh read offset (halves)
  const int hw = n*40 + 16*wave + 4*quad;  // h write offset (halves)
  const bool q0 = (quad == 0);
  const f16x8 zf8 = (f16x8)(_Float16)0;
  const float2* x2p = (const float2*)xstf;
  const int xb2 = n*195;                   // float2 index base for this batch

  for (int tc = 0; tc < Tlen; tc += 64) {
    // stage 64 steps x 16 batches x 5 inputs into padded [n][t][6] layout
    __syncthreads();   // protect xstf against stragglers of previous chunk
    for (int i = tidb; i < 5120; i += 128){
      const int nn = i/320, e = i%320;
      xstf[nn*390 + (e/5)*6 + (e%5)] =
        input[(size_t)(b0+nn)*(Tlen*NIN) + tc*5 + e];
    }
    __syncthreads();
    #pragma unroll 1
    for (int tl2 = 0; tl2 < 32; ++tl2) {
      // hoist x reads for BOTH half-steps (latency hides under par0 compute)
      const int base0 = xb2 + (2*tl2)*3;
      const float2 a0 = x2p[base0],   a1 = x2p[base0+1], a2 = x2p[base0+2];
      const float2 b1 = x2p[base0+3], b2 = x2p[base0+4], b3 = x2p[base0+5];
      #pragma unroll
      for (int par=0; par<2; ++par) {
        const _Float16* rbuf = hbufh + par*640;
        _Float16*       wbuf = hbufh + (par^1)*640;
        // B-frag (h-part) -- issue read early; ax-MFMAs don't depend on it
        const f16x8 bh = *(const f16x8*)(rbuf + hb);
        // B-frag (x-part): quad0 lanes carry [x0..x4,0,0,0]
        const float xv0 = par ? b1.x : a0.x;
        const float xv1 = par ? b1.y : a0.y;
        const float xv2 = par ? b2.x : a1.x;
        const float xv3 = par ? b2.y : a1.y;
        const float xv4 = par ? b3.x : a2.x;
        union { f16x8 v; h2v h[4]; } U;
        U.h[0].x=(_Float16)xv0; U.h[0].y=(_Float16)xv1;
        U.h[1].x=(_Float16)xv2; U.h[1].y=(_Float16)xv3;
        U.h[2].x=(_Float16)xv4; U.h[2].y=(_Float16)0;
        U.h[3]=(h2v)0;
        const f16x8 bx = q0 ? U.v : zf8;
        // 8 MFMAs: gates i,f,g,o (ax first; ah chained after bh arrives)
        f32x4 Ci = __builtin_amdgcn_mfma_f32_16x16x32_f16(ax[0], bx, bi[0], 0,0,0);
        f32x4 Cf = __builtin_amdgcn_mfma_f32_16x16x32_f16(ax[1], bx, bi[1], 0,0,0);
        f32x4 Cg = __builtin_amdgcn_mfma_f32_16x16x32_f16(ax[2], bx, bi[2], 0,0,0);
        f32x4 Co = __builtin_amdgcn_mfma_f32_16x16x32_f16(ax[3], bx, bi[3], 0,0,0);
        Ci = __builtin_amdgcn_mfma_f32_16x16x32_f16(ah[0], bh, Ci, 0,0,0);
        Cf = __builtin_amdgcn_mfma_f32_16x16x32_f16(ah[1], bh, Cf, 0,0,0);
        Cg = __builtin_amdgcn_mfma_f32_16x16x32_f16(ah[2], bh, Cg, 0,0,0);
        Co = __builtin_amdgcn_mfma_f32_16x16x32_f16(ah[3], bh, Co, 0,0,0);
        // activations: preacts arrive pre-scaled: sig = rcp(1+exp2(C));
        // g gate: tanh = 2*rcp(1+exp2(C)) - 1 (C already -2L2E*a)
        {
          const float iv = frcp(1.f + fexp2(Ci[0]));
          const float fv = frcp(1.f + fexp2(Cf[0]));
          const float gv = fmaf(2.f, frcp(1.f + fexp2(Cg[0])), -1.f);
          const float ov = frcp(1.f + fexp2(Co[0]));
          c0 = fmaf(fv, c0, iv*gv);
          const float r2 = frcp(1.f + fexp2((2.f*L2E)*c0));
          h0f = ov * fmaf(-2.f, r2, 1.f);
        }
        {
          const float iv = frcp(1.f + fexp2(Ci[1]));
          const float fv = frcp(1.f + fexp2(Cf[1]));
          const float gv = fmaf(2.f, frcp(1.f + fexp2(Cg[1])), -1.f);
          const float ov = frcp(1.f + fexp2(Co[1]));
          c1 = fmaf(fv, c1, iv*gv);
          const float r2 = frcp(1.f + fexp2((2.f*L2E)*c1));
          h1f = ov * fmaf(-2.f, r2, 1.f);
        }
        {
          const float iv = frcp(1.f + fexp2(Ci[2]));
          const float fv = frcp(1.f + fexp2(Cf[2]));
          const float gv = fmaf(2.f, frcp(1.f + fexp2(Cg[2])), -1.f);
          const float ov = frcp(1.f + fexp2(Co[2]));
          c2 = fmaf(fv, c2, iv*gv);
          const float r2 = frcp(1.f + fexp2((2.f*L2E)*c2));
          h2f = ov * fmaf(-2.f, r2, 1.f);
        }
        {
          const float iv = frcp(1.f + fexp2(Ci[3]));
          const float fv = frcp(1.f + fexp2(Cf[3]));
          const float gv = fmaf(2.f, frcp(1.f + fexp2(Cg[3])), -1.f);
          const float ov = frcp(1.f + fexp2(Co[3]));
          c3 = fmaf(fv, c3, iv*gv);
          const float r2 = frcp(1.f + fexp2((2.f*L2E)*c3));
          h3f = ov * fmaf(-2.f, r2, 1.f);
        }
        // pack h -> fp16, write 4 contiguous dims (8B)
        h2v q01, q23;
        q01.x=(_Float16)h0f; q01.y=(_Float16)h1f;
        q23.x=(_Float16)h2f; q23.y=(_Float16)h3f;
        float2 wv;
        wv.x = __builtin_bit_cast(float, q01);
        wv.y = __builtin_bit_cast(float, q23);
        *(float2*)(wbuf + hw) = wv;
        __syncthreads();
      }
    }
  }

  // ---- tail: stash fp32 h,c; project q(h), k(c), v(c) ----
  float* hf = xstf;            // [16][36]
  float* cf = xstf + 16*36;
  __syncthreads();
  {
    const int d0 = 16*wave + 4*quad;
    float4 hv4; hv4.x=h0f; hv4.y=h1f; hv4.z=h2f; hv4.w=h3f;
    float4 cv4; cv4.x=c0;  cv4.y=c1;  cv4.z=c2;  cv4.w=c3;
    *(float4*)(&hf[n*36 + d0]) = hv4;
    *(float4*)(&cf[n*36 + d0]) = cv4;
  }
  __syncthreads();
  for (int i = tidb; i < 16*NE; i += 128){
    const int nn = i/NE, d = i%NE;
    ho[(size_t)(b0+nn)*NE + d] = hf[nn*36 + d];
  }
  const float QS = 0.31622776601683794f;     // 1/sqrt(10)
  for (int i = tidb; i < 90*16; i += 128){
    const int o  = i % 90;
    const int nn = i / 90;
    const float* wrow = in_proj_w + o*NE;
    const float* src  = (o < NE) ? &hf[nn*36] : &cf[nn*36];
    float acc = in_proj_b[o];
    #pragma unroll
    for (int k2=0;k2<NE;k2++) acc = fmaf(wrow[k2], src[k2], acc);
    const int b = b0 + nn;
    if (o < 30)      { qo[(o/10)*B10 + b*10 + (o%10)] = acc * QS; }
    else if (o < 60) { const int u=o-30; ko[(u/10)*B10 + b*10 + (u%10)] = acc; }
    else             { const int u=o-60; vo[(u/10)*B10 + b*10 + (u%10)] = acc; }
  }
}

// ---------------------------------------------------------------------------
// Kernel 2: flash attention partials. 1 thread = 1 query row. (unchanged R7)
// grid = (16 qblocks, 3 heads, NS ksplits), block = 256. K/V addresses are
// wave-uniform -> scalar/broadcast loads.
// ---------------------------------------------------------------------------
extern "C" __global__ void __launch_bounds__(256)
attn_part(const float* __restrict__ q, const float* __restrict__ k,
          const float* __restrict__ v, float* __restrict__ part, int nkeys)
{
  const int t    = threadIdx.x;
  const int qr   = blockIdx.x*256 + t;
  const int head = blockIdx.y;
  const int ks   = blockIdx.z;
  const float* kh = k + (size_t)head*B10;
  const float* vh = v + (size_t)head*B10;
  float qreg[10];
  {
    const float2* qp = (const float2*)(q + (size_t)head*B10 + (size_t)qr*10);
    #pragma unroll
    for (int i=0;i<5;i++){ float2 t2=qp[i]; qreg[2*i]=t2.x; qreg[2*i+1]=t2.y; }
  }
  float m = -INFINITY, l = 0.f, acc[10];
  #pragma unroll
  for (int d=0;d<10;d++) acc[d]=0.f;

  const int k0 = ks * nkeys;
  #pragma unroll 1
  for (int cch=0; cch<nkeys; cch+=8) {
    const int kb = k0 + cch;           // wave-uniform
    float s[8];
    #pragma unroll
    for (int u=0;u<8;u++){
      const float* kp = kh + (size_t)(kb+u)*10;
      float sv = 0.f;
      #pragma unroll
      for (int i=0;i<10;i++) sv = fmaf(qreg[i], kp[i], sv);
      s[u]=sv;
    }
    float mc = s[0];
    #pragma unroll
    for (int u=1;u<8;u++) mc = fmaxf(mc, s[u]);
    const float mnew = fmaxf(m, mc);
    const float corr = fexp2(L2E*(m - mnew));   // m=-inf first chunk -> 0
    l *= corr;
    #pragma unroll
    for (int d=0;d<10;d++) acc[d]*=corr;
    #pragma unroll
    for (int u=0;u<8;u++){
      const float p = fexp2(L2E*(s[u]-mnew));
      l += p;
      const float* vp = vh + (size_t)(kb+u)*10;
      #pragma unroll
      for (int d=0;d<10;d++) acc[d] = fmaf(p, vp[d], acc[d]);
    }
    m = mnew;
  }
  float* pp = part + ((size_t)(head*Bsz + qr)*gridDim.z + ks)*12;
  pp[0]=m; pp[1]=l;
  #pragma unroll
  for (int d=0;d<10;d++) pp[2+d]=acc[d];
}

// ---------------------------------------------------------------------------
// Kernel 3: fused merge + out_proj + residual + LN + MLP + LN + head.
// One wave per row. Lane d<30 online-merges its (head=d/10, dim=d%10) ctx
// component from the NS partials inline (kills the attn_merge kernel + cx
// roundtrip -- tests the launch-overhead share of the 159us non-lstm gap).
// ---------------------------------------------------------------------------
extern "C" __global__ void __launch_bounds__(256)
tail_k(const float* __restrict__ part, int ns, const float* __restrict__ hn,
       const float* __restrict__ out_proj_w, const float* __restrict__ out_proj_b,
       const float* __restrict__ fc1_w, const float* __restrict__ fc1_b,
       const float* __restrict__ fc2_w, const float* __restrict__ fc2_b,
       const float* __restrict__ ln_g, const float* __restrict__ ln_b,
       const float* __restrict__ out_w, const float* __restrict__ out_b,
       float* __restrict__ out)
{
  __shared__ __align__(16) float buf[4][32];
  const int wave = threadIdx.x >> 6;
  const int lane = threadIdx.x & 63;
  const int b = blockIdx.x*4 + wave;
  const bool act = (lane < NE);
  if (lane < 32) buf[wave][lane] = 0.f;
  __builtin_amdgcn_wave_barrier();
  if (act) {
    const int head = lane/10, dd = lane%10;
    const float* p = part + ((size_t)(head*Bsz + b)*ns)*12;
    float M = -INFINITY, L = 0.f, O = 0.f;
    for (int i=0;i<ns;i++){
      const float mi = p[i*12], li = p[i*12+1], ai = p[i*12+2+dd];
      const float Mn = fmaxf(M, mi);
      const float cw = fexp2(L2E*(M - Mn));
      const float wi = fexp2(L2E*(mi - Mn));
      L = fmaf(li, wi, L*cw);
      O = fmaf(ai, wi, O*cw);
      M = Mn;
    }
    buf[wave][lane] = O / L;
  }
  __builtin_amdgcn_wave_barrier();
  float arr[32];
  loadarr32(arr, &buf[wave][0]);
  const float hv = act ? hn[b*NE+lane] : 0.f;
  float x = 0.f;
  if (act) {
    float a = out_proj_b[lane];
    #pragma unroll
    for (int k2=0;k2<NE;k2++) a = fmaf(out_proj_w[lane*NE+k2], arr[k2], a);
    x = a + hv;                       // attn_out + h_n
  }
  // LN1
  __builtin_amdgcn_wave_barrier();
  if (act) buf[wave][lane] = x;
  __builtin_amdgcn_wave_barrier();
  loadarr32(arr, &buf[wave][0]);
  float s1=0.f, s2=0.f;
  #pragma unroll
  for (int k2=0;k2<32;k2++){ s1+=arr[k2]; s2=fmaf(arr[k2],arr[k2],s2); }
  float mu = s1*(1.f/30.f);
  float var = s2*(1.f/30.f) - mu*mu;
  float rs = rsqrtf(var + 1e-5f);
  float x1 = 0.f;
  if (act) x1 = fmaf((x-mu)*rs, ln_g[lane], ln_b[lane]);
  // fc1 + exact GELU
  __builtin_amdgcn_wave_barrier();
  if (act) buf[wave][lane] = x1;
  __builtin_amdgcn_wave_barrier();
  loadarr32(arr, &buf[wave][0]);
  float gv = 0.f;
  if (act) {
    float a = fc1_b[lane];
    #pragma unroll
    for (int k2=0;k2<NE;k2++) a = fmaf(fc1_w[lane*NE+k2], arr[k2], a);
    gv = 0.5f*a*(1.f + erff(a*0.70710678118654752f));
  }
  // fc2
  __builtin_amdgcn_wave_barrier();
  if (act) buf[wave][lane] = gv;
  __builtin_amdgcn_wave_barrier();
  loadarr32(arr, &buf[wave][0]);
  float y = 0.f;
  if (act) {
    float a = fc2_b[lane];
    #pragma unroll
    for (int k2=0;k2<NE;k2++) a = fmaf(fc2_w[lane*NE+k2], arr[k2], a);
    y = x1 + a;                        // residual x1 + fc
  }
  // LN2
  __builtin_amdgcn_wave_barrier();
  if (act) buf[wave][lane] = y;
  __builtin_amdgcn_wave_barrier();
  loadarr32(arr, &buf[wave][0]);
  s1=0.f; s2=0.f;
  #pragma unroll
  for (int k2=0;k2<32;k2++){ s1+=arr[k2]; s2=fmaf(arr[k2],arr[k2],s2); }
  mu = s1*(1.f/30.f);
  var = s2*(1.f/30.f) - mu*mu;
  rs = rsqrtf(var + 1e-5f);
  float x2 = 0.f;
  if (act) x2 = fmaf((y-mu)*rs, ln_g[lane], ln_b[lane]);
  // head: [3,30]
  __builtin_amdgcn_wave_barrier();
  if (act) buf[wave][lane] = x2;
  __builtin_amdgcn_wave_barrier();
  loadarr32(arr, &buf[wave][0]);
  if (lane < 3) {
    float a = out_b[lane];
    #pragma unroll
    for (int k2=0;k2<NE;k2++) a = fmaf(out_w[lane*NE+k2], arr[k2], a);
    out[b*3 + lane] = a;
  }
}

extern "C" void kernel_launch(void* const* d_in, const int* in_sizes, int n_in,
                              void* d_out, int out_size, void* d_ws, size_t ws_size,
                              hipStream_t stream)
{
  const float* input      = (const float*)d_in[0];
  const float* w_ih       = (const float*)d_in[1];
  const float* w_hh       = (const float*)d_in[2];
  const float* b_ih       = (const float*)d_in[3];
  const float* b_hh       = (const float*)d_in[4];
  const float* in_proj_w  = (const float*)d_in[5];
  const float* in_proj_b  = (const float*)d_in[6];
  const float* out_proj_w = (const float*)d_in[7];
  const float* out_proj_b = (const float*)d_in[8];
  const float* fc1_w      = (const float*)d_in[9];
  const float* fc1_b      = (const float*)d_in[10];
  const float* fc2_w      = (const float*)d_in[11];
  const float* fc2_b      = (const float*)d_in[12];
  const float* ln_g       = (const float*)d_in[13];
  const float* ln_b       = (const float*)d_in[14];
  const float* out_w      = (const float*)d_in[15];
  const float* out_b      = (const float*)d_in[16];

  float* ws = (float*)d_ws;
  float* qo   = ws;                 // [3][4096][10]
  float* ko   = ws + 122880;        // [3][4096][10]
  float* vo   = ws + 245760;        // [3][4096][10]
  float* hn   = ws + 368640;        // [4096][30]
  float* part = ws + 491520;        // [3][4096][NS][12]

  const size_t need16 = ((size_t)491520 + (size_t)3*4096*16*12) * 4;
  const int NS = (ws_size >= need16) ? 16 : 8;

  lstm_k<<<Bsz/16, 128, 0, stream>>>(input, w_ih, w_hh, b_ih, b_hh,
                                     in_proj_w, in_proj_b, qo, ko, vo, hn);
  attn_part<<<dim3(Bsz/256, 3, NS), 256, 0, stream>>>(qo, ko, vo, part, Bsz/NS);
  tail_k<<<Bsz/4, 256, 0, stream>>>(part, NS, hn, out_proj_w, out_proj_b,
                                    fc1_w, fc1_b, fc2_w, fc2_b,
                                    ln_g, ln_b, out_w, out_b, (float*)d_out);
}